// Round 7
// baseline (2354.635 us; speedup 1.0000x reference)
//
#include <hip/hip_runtime.h>
#include <math.h>

#define NSCALE 0.44668359215096315f

__device__ __forceinline__ float eluf(float v)  { return v > 0.0f ? v : __expf(v) - 1.0f; }
__device__ __forceinline__ float reluf(float v) { return fmaxf(v, 0.0f); }

// ---------------- kW: one-time weight swizzle into ws (consumption-order layouts) ----------------
__global__ __launch_bounds__(256) void kW(const float* __restrict__ pc2w,
                                          const float* __restrict__ pc5w,
                                          const float* __restrict__ dl1w,
                                          float* __restrict__ pc2s,
                                          float* __restrict__ pc5s,
                                          float* __restrict__ dl1s)
{
    int tid = threadIdx.x;
    for (int j = tid; j < 512; j += 256) {            // pc2w[o*32+ci*2+tap] -> [tap][o][ci]
        int o = j >> 5, r = j & 31, ci = r >> 1, tap = r & 1;
        pc2s[tap*256 + o*16 + ci] = pc2w[j];
    }
    for (int j = tid; j < 768; j += 256) {            // pc5w[o*48+ci*3+g] -> [g][o][ci]
        int o = j / 48, r = j - o*48, ci = r / 3, g = r - ci*3;
        pc5s[g*256 + o*16 + ci] = pc5w[j];
    }
    for (int j = tid; j < 1024; j += 256) {           // dl1w[o*64+c*8+t] -> [t][o][c]
        int o = j >> 6, r = j & 63, c = r >> 3, t = r & 7;
        dl1s[t*128 + o*8 + c] = dl1w[j];
    }
}

// ---------------- kA: encoder -> z (stored to ws), per-block partial sums ----------------
__global__ __launch_bounds__(256) void kA(const float* __restrict__ x,
                                          const float* __restrict__ ew1, const float* __restrict__ eb1,
                                          const float* __restrict__ ew2, const float* __restrict__ eb2,
                                          float* __restrict__ partials, float* __restrict__ zout, int B)
{
    __shared__ float wsum[4][32];
    int tid = threadIdx.x;
    int i = blockIdx.x * 256 + tid;
    bool valid = i < B;
    float xv[16];
    if (valid) {
        const float4* xp = reinterpret_cast<const float4*>(x + (size_t)i * 16);
#pragma unroll
        for (int q = 0; q < 4; ++q) {
            float4 v = xp[q];
            xv[4*q+0] = v.x; xv[4*q+1] = v.y; xv[4*q+2] = v.z; xv[4*q+3] = v.w;
        }
    } else {
#pragma unroll
        for (int q = 0; q < 16; ++q) xv[q] = 0.0f;
    }

    float h1[16];
#pragma unroll
    for (int o = 0; o < 16; ++o) {
        float a = eb1[o];
#pragma unroll
        for (int k = 0; k < 16; ++k) a = fmaf(xv[k], ew1[o*16+k], a);
        h1[o] = eluf(a);
    }
    float z[16];
#pragma unroll
    for (int o = 0; o < 16; ++o) {
        float a = eb2[o];
#pragma unroll
        for (int k = 0; k < 16; ++k) a = fmaf(h1[k], ew2[o*16+k], a);
        z[o] = valid ? a : 0.0f;
    }

    if (valid) {
        float4* zp = reinterpret_cast<float4*>(zout + (size_t)i * 16);
        zp[0] = make_float4(z[0],  z[1],  z[2],  z[3]);
        zp[1] = make_float4(z[4],  z[5],  z[6],  z[7]);
        zp[2] = make_float4(z[8],  z[9],  z[10], z[11]);
        zp[3] = make_float4(z[12], z[13], z[14], z[15]);
    }

    int lane = tid & 63, wave = tid >> 6;
#pragma unroll
    for (int c = 0; c < 16; ++c) {
        float s = z[c];
        float q = z[c] * z[c];
#pragma unroll
        for (int m = 1; m < 64; m <<= 1) { s += __shfl_xor(s, m); q += __shfl_xor(q, m); }
        if (lane == 0) { wsum[wave][c] = s; wsum[wave][16 + c] = q; }
    }
    __syncthreads();
    if (tid < 32) {
        float t = wsum[0][tid] + wsum[1][tid] + wsum[2][tid] + wsum[3][tid];
        partials[(size_t)blockIdx.x * 32 + tid] = t;
    }
}

// ---------------- kB: reduce partials -> BN affine ----------------
__global__ __launch_bounds__(256) void kB(const float* __restrict__ partials, int nblk, int B,
                                          const float* __restrict__ bng, const float* __restrict__ bnb,
                                          float* __restrict__ bnp)
{
    int tid = threadIdx.x;
    int q = tid >> 3, k = tid & 7;
    int chunk = (nblk + 7) / 8;
    int j0 = k * chunk;
    int j1 = j0 + chunk; if (j1 > nblk) j1 = nblk;
    double s = 0.0;
    for (int j = j0; j < j1; ++j) s += (double)partials[(size_t)j * 32 + q];
    s += __shfl_xor(s, 4);
    s += __shfl_xor(s, 2);
    s += __shfl_xor(s, 1);
    __shared__ double tot[32];
    if (k == 0) tot[q] = s;
    __syncthreads();
    if (tid < 16) {
        double mu  = tot[tid] / (double)B;
        double var = tot[16 + tid] / (double)B - mu * mu;
        double a = (double)bng[tid] / sqrt(var + 1e-5);
        double b = (double)bnb[tid] - mu * a;
        bnp[tid]      = (float)a;
        bnp[16 + tid] = (float)b;
    }
}

// ---------------- LDS layouts (float offsets, float4-aligned) ----------------
constexpr int C_PC1W = 0;     // 64
constexpr int C_PC1B = 64;    // 16
constexpr int C_PC2W = 80;    // 512  [tap][o][ci]
constexpr int C_PC2B = 592;   // 16
constexpr int C_PC3W = 608;   // 512  [o][ci][tap]
constexpr int C_PC3B = 1120;  // 16
constexpr int C_PC4W = 1136;  // 256
constexpr int C_PC4B = 1392;  // 16
constexpr int C_PC5W = 1408;  // 768  [g][o][ci]
constexpr int C_PC5B = 2176;  // 16
constexpr int C_PLW  = 2192;  // 256
constexpr int C_PLB  = 2448;  // 16
constexpr int C_BNP  = 2464;  // 32
constexpr int C_TOT  = 2496;

constexpr int D_DC1W = 0;     // 8
constexpr int D_DC1B = 8;     // 8
constexpr int D_DC2W = 16;    // 128 [c][ci][tap]
constexpr int D_DC2B = 144;   // 8
constexpr int D_DC3W = 152;   // 64
constexpr int D_DC3B = 216;   // 8
constexpr int D_DC4W = 224;   // 64
constexpr int D_DC4B = 288;   // 8
constexpr int D_DL1  = 296;   // 1024 [t][o][c]
constexpr int D_DL1B = 1320;  // 16
constexpr int D_DL2W = 1336;  // 256
constexpr int D_DL2B = 1592;  // 16
constexpr int D_DL3W = 1608;  // 256
constexpr int D_DL3B = 1864;  // 16
constexpr int D_TOT  = 1880;

// ---------------- k23: BN+FIR+noise, p-convs + pl + equalizer; weights in LDS (f4 broadcast) ----------------
__global__ __launch_bounds__(256) void k23(float* __restrict__ crt,
    const float* __restrict__ fading, const float* __restrict__ noise,
    const float* __restrict__ bnp,
    const float* __restrict__ pc1w, const float* __restrict__ pc1b,
    const float* __restrict__ pc2s, const float* __restrict__ pc2b,
    const float* __restrict__ pc3w, const float* __restrict__ pc3b,
    const float* __restrict__ pc4w, const float* __restrict__ pc4b,
    const float* __restrict__ pc5s, const float* __restrict__ pc5b,
    const float* __restrict__ plw,  const float* __restrict__ plb,
    int B)
{
    __shared__ __align__(16) float Wl[C_TOT];
    int tid = threadIdx.x;
    if (tid < 64)  Wl[C_PC1W + tid] = pc1w[tid];
    if (tid < 16)  Wl[C_PC1B + tid] = pc1b[tid];
    for (int j = tid; j < 512; j += 256) Wl[C_PC2W + j] = pc2s[j];
    if (tid < 16)  Wl[C_PC2B + tid] = pc2b[tid];
    for (int j = tid; j < 512; j += 256) Wl[C_PC3W + j] = pc3w[j];
    if (tid < 16)  Wl[C_PC3B + tid] = pc3b[tid];
    if (tid < 256) Wl[C_PC4W + tid] = pc4w[tid];
    if (tid < 16)  Wl[C_PC4B + tid] = pc4b[tid];
    for (int j = tid; j < 768; j += 256) Wl[C_PC5W + j] = pc5s[j];
    if (tid < 16)  Wl[C_PC5B + tid] = pc5b[tid];
    if (tid < 256) Wl[C_PLW + tid] = plw[tid];
    if (tid < 16)  Wl[C_PLB + tid] = plb[tid];
    if (tid < 32)  Wl[C_BNP + tid] = bnp[tid];
    __syncthreads();

    int i = blockIdx.x * 256 + tid;
    if (i >= B) return;

    // ---- BN affine on z (in ws) ----
    float zn[16];
    {
        const float4* zp = reinterpret_cast<const float4*>(crt + (size_t)i * 16);
#pragma unroll
        for (int q = 0; q < 4; ++q) {
            float4 v = zp[q];
            zn[4*q+0] = fmaf(v.x, Wl[C_BNP + 4*q+0], Wl[C_BNP + 16 + 4*q+0]);
            zn[4*q+1] = fmaf(v.y, Wl[C_BNP + 4*q+1], Wl[C_BNP + 16 + 4*q+1]);
            zn[4*q+2] = fmaf(v.z, Wl[C_BNP + 4*q+2], Wl[C_BNP + 16 + 4*q+2]);
            zn[4*q+3] = fmaf(v.w, Wl[C_BNP + 4*q+3], Wl[C_BNP + 16 + 4*q+3]);
        }
    }
    // ---- FIR + noise ----
    float f[6];
    {
        const float2* fp = reinterpret_cast<const float2*>(fading + (size_t)i * 6);
#pragma unroll
        for (int q = 0; q < 3; ++q) { float2 v = fp[q]; f[2*q] = v.x; f[2*q+1] = v.y; }
    }
    float cr[16];
#pragma unroll
    for (int n = 0; n < 8; ++n) {
        float re = f[0]*zn[2*n]   - f[1]*zn[2*n+1];
        float im = f[0]*zn[2*n+1] + f[1]*zn[2*n];
        if (n >= 1) { re += f[2]*zn[2*n-2] - f[3]*zn[2*n-1];
                      im += f[2]*zn[2*n-1] + f[3]*zn[2*n-2]; }
        if (n >= 2) { re += f[4]*zn[2*n-4] - f[5]*zn[2*n-3];
                      im += f[4]*zn[2*n-3] + f[5]*zn[2*n-4]; }
        cr[2*n] = re; cr[2*n+1] = im;
    }
    {
        const float4* np_ = reinterpret_cast<const float4*>(noise + (size_t)i * 16);
#pragma unroll
        for (int q = 0; q < 4; ++q) {
            float4 v = np_[q];
            cr[4*q+0] = fmaf(v.x, NSCALE, cr[4*q+0]);
            cr[4*q+1] = fmaf(v.y, NSCALE, cr[4*q+1]);
            cr[4*q+2] = fmaf(v.z, NSCALE, cr[4*q+2]);
            cr[4*q+3] = fmaf(v.w, NSCALE, cr[4*q+3]);
        }
    }
    {
        float4* op = reinterpret_cast<float4*>(crt + (size_t)i * 16);
        op[0] = make_float4(cr[0],  cr[1],  cr[2],  cr[3]);
        op[1] = make_float4(cr[4],  cr[5],  cr[6],  cr[7]);
        op[2] = make_float4(cr[8],  cr[9],  cr[10], cr[11]);
        op[3] = make_float4(cr[12], cr[13], cr[14], cr[15]);
    }

    // ---- p-convs (g rolled; weights via LDS float4 broadcast) ----
    float p5a[16];
#pragma unroll
    for (int o = 0; o < 16; ++o) p5a[o] = Wl[C_PC5B + o];

#pragma unroll 1
    for (int g = 0; g < 3; ++g) {
        float crg[8];
        {
            const float4* cp = reinterpret_cast<const float4*>(crt + (size_t)i * 16 + 4 * g);
            float4 v0 = cp[0], v1 = cp[1];
            crg[0]=v0.x; crg[1]=v0.y; crg[2]=v0.z; crg[3]=v0.w;
            crg[4]=v1.x; crg[5]=v1.y; crg[6]=v1.z; crg[7]=v1.w;
        }
        float p1c[3][16];
#pragma unroll
        for (int c2 = 0; c2 < 3; ++c2) {
#pragma unroll
            for (int o = 0; o < 16; ++o) {
                float4 w = *reinterpret_cast<const float4*>(&Wl[C_PC1W + o*4]);
                float a = Wl[C_PC1B + o];
                a = fmaf(w.x, crg[c2+0], a);
                a = fmaf(w.y, crg[c2+1], a);
                a = fmaf(w.z, crg[c2+2], a);
                a = fmaf(w.w, crg[c2+3], a);
                p1c[c2][o] = reluf(a);
            }
        }
        float p2c[2][16];
#pragma unroll
        for (int c2 = 0; c2 < 2; ++c2) {
#pragma unroll
            for (int o = 0; o < 16; ++o) {
                float a = Wl[C_PC2B + o];
#pragma unroll
                for (int q = 0; q < 4; ++q) {
                    float4 w = *reinterpret_cast<const float4*>(&Wl[C_PC2W + o*16 + 4*q]);
                    a = fmaf(w.x, p1c[c2][4*q+0], a);
                    a = fmaf(w.y, p1c[c2][4*q+1], a);
                    a = fmaf(w.z, p1c[c2][4*q+2], a);
                    a = fmaf(w.w, p1c[c2][4*q+3], a);
                }
#pragma unroll
                for (int q = 0; q < 4; ++q) {
                    float4 w = *reinterpret_cast<const float4*>(&Wl[C_PC2W + 256 + o*16 + 4*q]);
                    a = fmaf(w.x, p1c[c2+1][4*q+0], a);
                    a = fmaf(w.y, p1c[c2+1][4*q+1], a);
                    a = fmaf(w.z, p1c[c2+1][4*q+2], a);
                    a = fmaf(w.w, p1c[c2+1][4*q+3], a);
                }
                p2c[c2][o] = reluf(a);
            }
        }
        float p3[16];
#pragma unroll
        for (int o = 0; o < 16; ++o) {
            float a = Wl[C_PC3B + o];
#pragma unroll
            for (int q = 0; q < 8; ++q) {
                float4 w = *reinterpret_cast<const float4*>(&Wl[C_PC3W + o*32 + 4*q]);
                a = fmaf(w.x, p2c[0][2*q+0], a);
                a = fmaf(w.y, p2c[1][2*q+0], a);
                a = fmaf(w.z, p2c[0][2*q+1], a);
                a = fmaf(w.w, p2c[1][2*q+1], a);
            }
            p3[o] = reluf(a);
        }
        float p4[16];
#pragma unroll
        for (int o = 0; o < 16; ++o) {
            float a = Wl[C_PC4B + o];
#pragma unroll
            for (int q = 0; q < 4; ++q) {
                float4 w = *reinterpret_cast<const float4*>(&Wl[C_PC4W + o*16 + 4*q]);
                a = fmaf(w.x, p3[4*q+0], a);
                a = fmaf(w.y, p3[4*q+1], a);
                a = fmaf(w.z, p3[4*q+2], a);
                a = fmaf(w.w, p3[4*q+3], a);
            }
            p4[o] = reluf(a);
        }
#pragma unroll
        for (int o = 0; o < 16; ++o) {
            float a = p5a[o];
#pragma unroll
            for (int q = 0; q < 4; ++q) {
                float4 w = *reinterpret_cast<const float4*>(&Wl[C_PC5W + g*256 + o*16 + 4*q]);
                a = fmaf(w.x, p4[4*q+0], a);
                a = fmaf(w.y, p4[4*q+1], a);
                a = fmaf(w.z, p4[4*q+2], a);
                a = fmaf(w.w, p4[4*q+3], a);
            }
            p5a[o] = a;
        }
    }

    float p5r[16];
#pragma unroll
    for (int o = 0; o < 16; ++o) p5r[o] = reluf(p5a[o]);
    float hh[16];
#pragma unroll
    for (int o = 0; o < 16; ++o) {
        float a = Wl[C_PLB + o];
#pragma unroll
        for (int q = 0; q < 4; ++q) {
            float4 w = *reinterpret_cast<const float4*>(&Wl[C_PLW + o*16 + 4*q]);
            a = fmaf(w.x, p5r[4*q+0], a);
            a = fmaf(w.y, p5r[4*q+1], a);
            a = fmaf(w.z, p5r[4*q+2], a);
            a = fmaf(w.w, p5r[4*q+3], a);
        }
        hh[o] = a;
    }

    // ---- equalizer (cr still in registers) ----
    float tr[16];
#pragma unroll
    for (int n = 0; n < 8; ++n) {
        float a = cr[2*n], b = cr[2*n+1];
        float c = hh[2*n], d = hh[2*n+1];
        float inv = 1.0f / (c*c + d*d);
        tr[2*n]   = (a*c + b*d) * inv;
        tr[2*n+1] = (b*c - a*d) * inv;
    }
    float4* op = reinterpret_cast<float4*>(crt + (size_t)i * 16);
    op[0] = make_float4(tr[0],  tr[1],  tr[2],  tr[3]);
    op[1] = make_float4(tr[4],  tr[5],  tr[6],  tr[7]);
    op[2] = make_float4(tr[8],  tr[9],  tr[10], tr[11]);
    op[3] = make_float4(tr[12], tr[13], tr[14], tr[15]);
}

// ---------------- k4: d-convs + dl1/dl2/dl3; weights in LDS (f4 broadcast) ----------------
__global__ __launch_bounds__(256) void k4(const float* __restrict__ trt,
    const float* __restrict__ dc1w, const float* __restrict__ dc1b,
    const float* __restrict__ dc2w, const float* __restrict__ dc2b,
    const float* __restrict__ dc3w, const float* __restrict__ dc3b,
    const float* __restrict__ dc4w, const float* __restrict__ dc4b,
    const float* __restrict__ dl1s, const float* __restrict__ dl1b,
    const float* __restrict__ dl2w, const float* __restrict__ dl2b,
    const float* __restrict__ dl3w, const float* __restrict__ dl3b,
    float* __restrict__ out, int B)
{
    __shared__ __align__(16) float Wl[D_TOT];
    int tid = threadIdx.x;
    if (tid < 8)   Wl[D_DC1W + tid] = dc1w[tid];
    if (tid < 8)   Wl[D_DC1B + tid] = dc1b[tid];
    if (tid < 128) Wl[D_DC2W + tid] = dc2w[tid];
    if (tid < 8)   Wl[D_DC2B + tid] = dc2b[tid];
    if (tid < 64)  Wl[D_DC3W + tid] = dc3w[tid];
    if (tid < 8)   Wl[D_DC3B + tid] = dc3b[tid];
    if (tid < 64)  Wl[D_DC4W + tid] = dc4w[tid];
    if (tid < 8)   Wl[D_DC4B + tid] = dc4b[tid];
    for (int j = tid; j < 1024; j += 256) Wl[D_DL1 + j] = dl1s[j];
    if (tid < 16)  Wl[D_DL1B + tid] = dl1b[tid];
    if (tid < 256) Wl[D_DL2W + tid] = dl2w[tid];
    if (tid < 16)  Wl[D_DL2B + tid] = dl2b[tid];
    if (tid < 256) Wl[D_DL3W + tid] = dl3w[tid];
    if (tid < 16)  Wl[D_DL3B + tid] = dl3b[tid];
    __syncthreads();

    int i = blockIdx.x * 256 + tid;
    if (i >= B) return;

    // hoist dc1 (loop-invariant, literal-indexed)
    float w1_[8], b1_[8];
#pragma unroll
    for (int c = 0; c < 8; ++c) { w1_[c] = Wl[D_DC1W + c]; b1_[c] = Wl[D_DC1B + c]; }

    float y[16];
#pragma unroll
    for (int o = 0; o < 16; ++o) y[o] = Wl[D_DL1B + o];

#pragma unroll 1
    for (int t = 0; t < 8; ++t) {
        float2 tv = *reinterpret_cast<const float2*>(trt + (size_t)i * 16 + 2 * t);
        float d1a[8], d1b[8];
#pragma unroll
        for (int c = 0; c < 8; ++c) {
            d1a[c] = reluf(fmaf(w1_[c], tv.x, b1_[c]));
            d1b[c] = reluf(fmaf(w1_[c], tv.y, b1_[c]));
        }
        float d2[8];
#pragma unroll
        for (int c = 0; c < 8; ++c) {
            float a = Wl[D_DC2B + c];
#pragma unroll
            for (int q = 0; q < 4; ++q) {
                float4 w = *reinterpret_cast<const float4*>(&Wl[D_DC2W + c*16 + 4*q]);
                a = fmaf(w.x, d1a[2*q+0], a);
                a = fmaf(w.y, d1b[2*q+0], a);
                a = fmaf(w.z, d1a[2*q+1], a);
                a = fmaf(w.w, d1b[2*q+1], a);
            }
            d2[c] = reluf(a);
        }
        float d3[8];
#pragma unroll
        for (int c = 0; c < 8; ++c) {
            float a = Wl[D_DC3B + c];
#pragma unroll
            for (int q = 0; q < 2; ++q) {
                float4 w = *reinterpret_cast<const float4*>(&Wl[D_DC3W + c*8 + 4*q]);
                a = fmaf(w.x, d2[4*q+0], a);
                a = fmaf(w.y, d2[4*q+1], a);
                a = fmaf(w.z, d2[4*q+2], a);
                a = fmaf(w.w, d2[4*q+3], a);
            }
            d3[c] = reluf(a);
        }
        float d4[8];
#pragma unroll
        for (int c = 0; c < 8; ++c) {
            float a = Wl[D_DC4B + c];
#pragma unroll
            for (int q = 0; q < 2; ++q) {
                float4 w = *reinterpret_cast<const float4*>(&Wl[D_DC4W + c*8 + 4*q]);
                a = fmaf(w.x, d3[4*q+0], a);
                a = fmaf(w.y, d3[4*q+1], a);
                a = fmaf(w.z, d3[4*q+2], a);
                a = fmaf(w.w, d3[4*q+3], a);
            }
            d4[c] = reluf(a);
        }
#pragma unroll
        for (int o = 0; o < 16; ++o) {
            float a = y[o];
#pragma unroll
            for (int q = 0; q < 2; ++q) {
                float4 w = *reinterpret_cast<const float4*>(&Wl[D_DL1 + t*128 + o*8 + 4*q]);
                a = fmaf(w.x, d4[4*q+0], a);
                a = fmaf(w.y, d4[4*q+1], a);
                a = fmaf(w.z, d4[4*q+2], a);
                a = fmaf(w.w, d4[4*q+3], a);
            }
            y[o] = a;
        }
    }
#pragma unroll
    for (int o = 0; o < 16; ++o) y[o] = reluf(y[o]);
    float h2[16];
#pragma unroll
    for (int o = 0; o < 16; ++o) {
        float a = Wl[D_DL2B + o];
#pragma unroll
        for (int q = 0; q < 4; ++q) {
            float4 w = *reinterpret_cast<const float4*>(&Wl[D_DL2W + o*16 + 4*q]);
            a = fmaf(w.x, y[4*q+0], a);
            a = fmaf(w.y, y[4*q+1], a);
            a = fmaf(w.z, y[4*q+2], a);
            a = fmaf(w.w, y[4*q+3], a);
        }
        h2[o] = eluf(a);
    }
    float o16[16];
#pragma unroll
    for (int o = 0; o < 16; ++o) {
        float a = Wl[D_DL3B + o];
#pragma unroll
        for (int q = 0; q < 4; ++q) {
            float4 w = *reinterpret_cast<const float4*>(&Wl[D_DL3W + o*16 + 4*q]);
            a = fmaf(w.x, h2[4*q+0], a);
            a = fmaf(w.y, h2[4*q+1], a);
            a = fmaf(w.z, h2[4*q+2], a);
            a = fmaf(w.w, h2[4*q+3], a);
        }
        o16[o] = a;
    }
    float4* op = reinterpret_cast<float4*>(out + (size_t)i * 16);
    op[0] = make_float4(o16[0],  o16[1],  o16[2],  o16[3]);
    op[1] = make_float4(o16[4],  o16[5],  o16[6],  o16[7]);
    op[2] = make_float4(o16[8],  o16[9],  o16[10], o16[11]);
    op[3] = make_float4(o16[12], o16[13], o16[14], o16[15]);
}

extern "C" void kernel_launch(void* const* d_in, const int* in_sizes, int n_in,
                              void* d_out, int out_size, void* d_ws, size_t ws_size,
                              hipStream_t stream)
{
    const float* x      = (const float*)d_in[0];
    const float* noise  = (const float*)d_in[1];
    const float* fading = (const float*)d_in[2];
    const float* ew1  = (const float*)d_in[3];
    const float* eb1  = (const float*)d_in[4];
    const float* ew2  = (const float*)d_in[5];
    const float* eb2  = (const float*)d_in[6];
    const float* bng  = (const float*)d_in[7];
    const float* bnb  = (const float*)d_in[8];
    const float* pc1w = (const float*)d_in[9];
    const float* pc1b = (const float*)d_in[10];
    const float* pc2w = (const float*)d_in[11];
    const float* pc2b = (const float*)d_in[12];
    const float* pc3w = (const float*)d_in[13];
    const float* pc3b = (const float*)d_in[14];
    const float* pc4w = (const float*)d_in[15];
    const float* pc4b = (const float*)d_in[16];
    const float* pc5w = (const float*)d_in[17];
    const float* pc5b = (const float*)d_in[18];
    const float* plw  = (const float*)d_in[19];
    const float* plb  = (const float*)d_in[20];
    const float* dc1w = (const float*)d_in[21];
    const float* dc1b = (const float*)d_in[22];
    const float* dc2w = (const float*)d_in[23];
    const float* dc2b = (const float*)d_in[24];
    const float* dc3w = (const float*)d_in[25];
    const float* dc3b = (const float*)d_in[26];
    const float* dc4w = (const float*)d_in[27];
    const float* dc4b = (const float*)d_in[28];
    const float* dl1w = (const float*)d_in[29];
    const float* dl1b = (const float*)d_in[30];
    const float* dl2w = (const float*)d_in[31];
    const float* dl2b = (const float*)d_in[32];
    const float* dl3w = (const float*)d_in[33];
    const float* dl3b = (const float*)d_in[34];

    int B = in_sizes[0] / 16;
    int nblk = (B + 255) / 256;

    float* partials = (float*)d_ws;                    // nblk*32
    float* bnp  = partials + (size_t)nblk * 32;        // 32
    float* pc2s = bnp + 32;                            // 512
    float* pc5s = pc2s + 512;                          // 768
    float* dl1s = pc5s + 768;                          // 1024
    float* crt  = dl1s + 1024;                         // B*16 (z -> cr -> tr in-place)

    kW<<<1, 256, 0, stream>>>(pc2w, pc5w, dl1w, pc2s, pc5s, dl1s);
    kA<<<nblk, 256, 0, stream>>>(x, ew1, eb1, ew2, eb2, partials, crt, B);
    kB<<<1, 256, 0, stream>>>(partials, nblk, B, bng, bnb, bnp);
    k23<<<nblk, 256, 0, stream>>>(crt, fading, noise, bnp,
                                  pc1w, pc1b, pc2s, pc2b, pc3w, pc3b, pc4w, pc4b, pc5s, pc5b,
                                  plw, plb, B);
    k4<<<nblk, 256, 0, stream>>>(crt,
                                 dc1w, dc1b, dc2w, dc2b, dc3w, dc3b, dc4w, dc4b,
                                 dl1s, dl1b, dl2w, dl2b, dl3w, dl3b,
                                 (float*)d_out, B);
}

// Round 8
// 914.948 us; speedup vs baseline: 2.5735x; 2.5735x over previous
//
#include <hip/hip_runtime.h>
#include <math.h>

#define NSCALE 0.44668359215096315f

__device__ __forceinline__ float eluf(float v)  { return v > 0.0f ? v : __expf(v) - 1.0f; }
__device__ __forceinline__ float reluf(float v) { return fmaxf(v, 0.0f); }

// exchange own 8 -> canonical full 16 across lane pair (sub=0: ch0-7, sub=1: ch8-15)
__device__ __forceinline__ void exch8(const float own[8], float full[16], int sub) {
#pragma unroll
    for (int j = 0; j < 8; ++j) {
        float oth = __shfl_xor(own[j], 1);
        full[j]     = sub ? oth    : own[j];
        full[8 + j] = sub ? own[j] : oth;
    }
}
__device__ __forceinline__ void exch4(const float own[4], float full[8], int sub) {
#pragma unroll
    for (int j = 0; j < 4; ++j) {
        float oth = __shfl_xor(own[j], 1);
        full[j]     = sub ? oth    : own[j];
        full[4 + j] = sub ? own[j] : oth;
    }
}

// ---------------- kW: one-time weight swizzle (consumption-order layouts) ----------------
__global__ __launch_bounds__(256) void kW(const float* __restrict__ pc2w,
                                          const float* __restrict__ pc5w,
                                          const float* __restrict__ dl1w,
                                          float* __restrict__ pc2s,
                                          float* __restrict__ pc5s,
                                          float* __restrict__ dl1s)
{
    int tid = threadIdx.x;
    for (int j = tid; j < 512; j += 256) {            // pc2w[o*32+ci*2+tap] -> [tap][o][ci]
        int o = j >> 5, r = j & 31, ci = r >> 1, tap = r & 1;
        pc2s[tap*256 + o*16 + ci] = pc2w[j];
    }
    for (int j = tid; j < 768; j += 256) {            // pc5w[o*48+ci*3+g] -> [g][o][ci]
        int o = j / 48, r = j - o*48, ci = r / 3, g = r - ci*3;
        pc5s[g*256 + o*16 + ci] = pc5w[j];
    }
    for (int j = tid; j < 1024; j += 256) {           // dl1w[o*64+c*8+t] -> [t][o][c]
        int o = j >> 6, r = j & 63, c = r >> 3, t = r & 7;
        dl1s[t*128 + o*8 + c] = dl1w[j];
    }
}

// ---------------- kA: encoder -> z (stored to ws), per-block partial sums ----------------
__global__ __launch_bounds__(256) void kA(const float* __restrict__ x,
                                          const float* __restrict__ ew1, const float* __restrict__ eb1,
                                          const float* __restrict__ ew2, const float* __restrict__ eb2,
                                          float* __restrict__ partials, float* __restrict__ zout, int B)
{
    __shared__ float wsum[4][32];
    int tid = threadIdx.x;
    int i = blockIdx.x * 256 + tid;
    bool valid = i < B;
    float xv[16];
    if (valid) {
        const float4* xp = reinterpret_cast<const float4*>(x + (size_t)i * 16);
#pragma unroll
        for (int q = 0; q < 4; ++q) {
            float4 v = xp[q];
            xv[4*q+0] = v.x; xv[4*q+1] = v.y; xv[4*q+2] = v.z; xv[4*q+3] = v.w;
        }
    } else {
#pragma unroll
        for (int q = 0; q < 16; ++q) xv[q] = 0.0f;
    }

    float h1[16];
#pragma unroll
    for (int o = 0; o < 16; ++o) {
        float a = eb1[o];
#pragma unroll
        for (int k = 0; k < 16; ++k) a = fmaf(xv[k], ew1[o*16+k], a);
        h1[o] = eluf(a);
    }
    float z[16];
#pragma unroll
    for (int o = 0; o < 16; ++o) {
        float a = eb2[o];
#pragma unroll
        for (int k = 0; k < 16; ++k) a = fmaf(h1[k], ew2[o*16+k], a);
        z[o] = valid ? a : 0.0f;
    }

    if (valid) {
        float4* zp = reinterpret_cast<float4*>(zout + (size_t)i * 16);
        zp[0] = make_float4(z[0],  z[1],  z[2],  z[3]);
        zp[1] = make_float4(z[4],  z[5],  z[6],  z[7]);
        zp[2] = make_float4(z[8],  z[9],  z[10], z[11]);
        zp[3] = make_float4(z[12], z[13], z[14], z[15]);
    }

    int lane = tid & 63, wave = tid >> 6;
#pragma unroll
    for (int c = 0; c < 16; ++c) {
        float s = z[c];
        float q = z[c] * z[c];
#pragma unroll
        for (int m = 1; m < 64; m <<= 1) { s += __shfl_xor(s, m); q += __shfl_xor(q, m); }
        if (lane == 0) { wsum[wave][c] = s; wsum[wave][16 + c] = q; }
    }
    __syncthreads();
    if (tid < 32) {
        float t = wsum[0][tid] + wsum[1][tid] + wsum[2][tid] + wsum[3][tid];
        partials[(size_t)blockIdx.x * 32 + tid] = t;
    }
}

// ---------------- kB: reduce partials -> BN affine ----------------
__global__ __launch_bounds__(256) void kB(const float* __restrict__ partials, int nblk, int B,
                                          const float* __restrict__ bng, const float* __restrict__ bnb,
                                          float* __restrict__ bnp)
{
    int tid = threadIdx.x;
    int q = tid >> 3, k = tid & 7;
    int chunk = (nblk + 7) / 8;
    int j0 = k * chunk;
    int j1 = j0 + chunk; if (j1 > nblk) j1 = nblk;
    double s = 0.0;
    for (int j = j0; j < j1; ++j) s += (double)partials[(size_t)j * 32 + q];
    s += __shfl_xor(s, 4);
    s += __shfl_xor(s, 2);
    s += __shfl_xor(s, 1);
    __shared__ double tot[32];
    if (k == 0) tot[q] = s;
    __syncthreads();
    if (tid < 16) {
        double mu  = tot[tid] / (double)B;
        double var = tot[16 + tid] / (double)B - mu * mu;
        double a = (double)bng[tid] / sqrt(var + 1e-5);
        double b = (double)bnb[tid] - mu * a;
        bnp[tid]      = (float)a;
        bnp[16 + tid] = (float)b;
    }
}

// ---------------- k23s: 2 threads/element. BN+FIR+noise + p-convs + pl + eq ----------------
__global__ __launch_bounds__(256) void k23s(float* __restrict__ crt,
    const float* __restrict__ fading, const float* __restrict__ noise,
    const float* __restrict__ bnp,
    const float* __restrict__ pc1w, const float* __restrict__ pc1b,
    const float* __restrict__ pc2s, const float* __restrict__ pc2b,
    const float* __restrict__ pc3w, const float* __restrict__ pc3b,
    const float* __restrict__ pc4w, const float* __restrict__ pc4b,
    const float* __restrict__ pc5s, const float* __restrict__ pc5b,
    const float* __restrict__ plw,  const float* __restrict__ plb,
    int B)
{
    int gt  = blockIdx.x * 256 + threadIdx.x;
    int i   = gt >> 1;
    int sub = gt & 1;
    if (i >= B) return;

    // per-lane weight bases (own output rows)
    const float* pc1wS = pc1w + sub * 32;   // row stride 4
    const float* pc1bS = pc1b + sub * 8;
    const float* pc2sS = pc2s + sub * 128;  // [tap(256)][o(16)][ci]
    const float* pc2bS = pc2b + sub * 8;
    const float* pc3wS = pc3w + sub * 256;  // row stride 32
    const float* pc3bS = pc3b + sub * 8;
    const float* pc4wS = pc4w + sub * 128;  // row stride 16
    const float* pc4bS = pc4b + sub * 8;
    const float* pc5sS = pc5s + sub * 128;  // [g(256)][o(16)][ci]
    const float* pc5bS = pc5b + sub * 8;
    const float* plwS  = plw  + sub * 128;
    const float* plbS  = plb  + sub * 8;

    // ---- head (duplicated in pair): BN affine + FIR + noise -> full cr ----
    float zn[16];
    {
        const float4* zp = reinterpret_cast<const float4*>(crt + (size_t)i * 16);
#pragma unroll
        for (int q = 0; q < 4; ++q) {
            float4 v = zp[q];
            zn[4*q+0] = fmaf(v.x, bnp[4*q+0], bnp[16 + 4*q+0]);
            zn[4*q+1] = fmaf(v.y, bnp[4*q+1], bnp[16 + 4*q+1]);
            zn[4*q+2] = fmaf(v.z, bnp[4*q+2], bnp[16 + 4*q+2]);
            zn[4*q+3] = fmaf(v.w, bnp[4*q+3], bnp[16 + 4*q+3]);
        }
    }
    float f[6];
    {
        const float2* fp = reinterpret_cast<const float2*>(fading + (size_t)i * 6);
#pragma unroll
        for (int q = 0; q < 3; ++q) { float2 v = fp[q]; f[2*q] = v.x; f[2*q+1] = v.y; }
    }
    float cr[16];
#pragma unroll
    for (int n = 0; n < 8; ++n) {
        float re = f[0]*zn[2*n]   - f[1]*zn[2*n+1];
        float im = f[0]*zn[2*n+1] + f[1]*zn[2*n];
        if (n >= 1) { re += f[2]*zn[2*n-2] - f[3]*zn[2*n-1];
                      im += f[2]*zn[2*n-1] + f[3]*zn[2*n-2]; }
        if (n >= 2) { re += f[4]*zn[2*n-4] - f[5]*zn[2*n-3];
                      im += f[4]*zn[2*n-3] + f[5]*zn[2*n-4]; }
        cr[2*n] = re; cr[2*n+1] = im;
    }
    {
        const float4* np_ = reinterpret_cast<const float4*>(noise + (size_t)i * 16);
#pragma unroll
        for (int q = 0; q < 4; ++q) {
            float4 v = np_[q];
            cr[4*q+0] = fmaf(v.x, NSCALE, cr[4*q+0]);
            cr[4*q+1] = fmaf(v.y, NSCALE, cr[4*q+1]);
            cr[4*q+2] = fmaf(v.z, NSCALE, cr[4*q+2]);
            cr[4*q+3] = fmaf(v.w, NSCALE, cr[4*q+3]);
        }
    }
    // own half (literal-index select), keep live for equalizer
    float crOwn[8];
#pragma unroll
    for (int j = 0; j < 8; ++j) crOwn[j] = sub ? cr[8 + j] : cr[j];
    // store own half so the rolled g-loop can reload slices (proven idiom)
    {
        float4* cw = reinterpret_cast<float4*>(crt + (size_t)i * 16 + sub * 8);
        cw[0] = make_float4(crOwn[0], crOwn[1], crOwn[2], crOwn[3]);
        cw[1] = make_float4(crOwn[4], crOwn[5], crOwn[6], crOwn[7]);
    }

    // ---- p-convs (g rolled) ----
    float p5a[8];
#pragma unroll
    for (int j = 0; j < 8; ++j) p5a[j] = pc5bS[j];

#pragma unroll 1
    for (int g = 0; g < 3; ++g) {
        float crg[8];
        {
            const float4* cp = reinterpret_cast<const float4*>(crt + (size_t)i * 16 + 4 * g);
            float4 v0 = cp[0], v1 = cp[1];
            crg[0]=v0.x; crg[1]=v0.y; crg[2]=v0.z; crg[3]=v0.w;
            crg[4]=v1.x; crg[5]=v1.y; crg[6]=v1.z; crg[7]=v1.w;
        }

        float q0o[8], q1o[8];
#pragma unroll
        for (int j = 0; j < 8; ++j) { float b = pc2bS[j]; q0o[j] = b; q1o[j] = b; }

        // ---- t-step 0: p1(col0) -> q0 via tap0 ----
        {
            float own[8];
#pragma unroll
            for (int j = 0; j < 8; ++j) {
                float4 w = *reinterpret_cast<const float4*>(pc1wS + j*4);
                float a = pc1bS[j];
                a = fmaf(w.x, crg[0], a); a = fmaf(w.y, crg[1], a);
                a = fmaf(w.z, crg[2], a); a = fmaf(w.w, crg[3], a);
                own[j] = reluf(a);
            }
            float pF[16]; exch8(own, pF, sub);
#pragma unroll
            for (int j = 0; j < 8; ++j) {
                float a = q0o[j];
#pragma unroll
                for (int q = 0; q < 4; ++q) {
                    float4 w = *reinterpret_cast<const float4*>(pc2sS + j*16 + 4*q);
                    a = fmaf(w.x, pF[4*q+0], a); a = fmaf(w.y, pF[4*q+1], a);
                    a = fmaf(w.z, pF[4*q+2], a); a = fmaf(w.w, pF[4*q+3], a);
                }
                q0o[j] = a;
            }
        }
        // ---- t-step 1: p1(col1) -> q1 via tap0, q0 via tap1 ----
        {
            float own[8];
#pragma unroll
            for (int j = 0; j < 8; ++j) {
                float4 w = *reinterpret_cast<const float4*>(pc1wS + j*4);
                float a = pc1bS[j];
                a = fmaf(w.x, crg[1], a); a = fmaf(w.y, crg[2], a);
                a = fmaf(w.z, crg[3], a); a = fmaf(w.w, crg[4], a);
                own[j] = reluf(a);
            }
            float pF[16]; exch8(own, pF, sub);
#pragma unroll
            for (int j = 0; j < 8; ++j) {
                float a1 = q1o[j];
#pragma unroll
                for (int q = 0; q < 4; ++q) {
                    float4 w = *reinterpret_cast<const float4*>(pc2sS + j*16 + 4*q);
                    a1 = fmaf(w.x, pF[4*q+0], a1); a1 = fmaf(w.y, pF[4*q+1], a1);
                    a1 = fmaf(w.z, pF[4*q+2], a1); a1 = fmaf(w.w, pF[4*q+3], a1);
                }
                q1o[j] = a1;
            }
#pragma unroll
            for (int j = 0; j < 8; ++j) {
                float a0 = q0o[j];
#pragma unroll
                for (int q = 0; q < 4; ++q) {
                    float4 w = *reinterpret_cast<const float4*>(pc2sS + 256 + j*16 + 4*q);
                    a0 = fmaf(w.x, pF[4*q+0], a0); a0 = fmaf(w.y, pF[4*q+1], a0);
                    a0 = fmaf(w.z, pF[4*q+2], a0); a0 = fmaf(w.w, pF[4*q+3], a0);
                }
                q0o[j] = a0;
            }
        }
        // ---- t-step 2: p1(col2) -> q1 via tap1 ----
        {
            float own[8];
#pragma unroll
            for (int j = 0; j < 8; ++j) {
                float4 w = *reinterpret_cast<const float4*>(pc1wS + j*4);
                float a = pc1bS[j];
                a = fmaf(w.x, crg[2], a); a = fmaf(w.y, crg[3], a);
                a = fmaf(w.z, crg[4], a); a = fmaf(w.w, crg[5], a);
                own[j] = reluf(a);
            }
            float pF[16]; exch8(own, pF, sub);
#pragma unroll
            for (int j = 0; j < 8; ++j) {
                float a = q1o[j];
#pragma unroll
                for (int q = 0; q < 4; ++q) {
                    float4 w = *reinterpret_cast<const float4*>(pc2sS + 256 + j*16 + 4*q);
                    a = fmaf(w.x, pF[4*q+0], a); a = fmaf(w.y, pF[4*q+1], a);
                    a = fmaf(w.z, pF[4*q+2], a); a = fmaf(w.w, pF[4*q+3], a);
                }
                q1o[j] = a;
            }
        }
#pragma unroll
        for (int j = 0; j < 8; ++j) { q0o[j] = reluf(q0o[j]); q1o[j] = reluf(q1o[j]); }
        float p2F0[16], p2F1[16];
        exch8(q0o, p2F0, sub);
        exch8(q1o, p2F1, sub);

        // ---- p3 ----
        float own3[8];
#pragma unroll
        for (int j = 0; j < 8; ++j) {
            float a = pc3bS[j];
#pragma unroll
            for (int q = 0; q < 8; ++q) {
                float4 w = *reinterpret_cast<const float4*>(pc3wS + j*32 + 4*q);
                a = fmaf(w.x, p2F0[2*q+0], a); a = fmaf(w.y, p2F1[2*q+0], a);
                a = fmaf(w.z, p2F0[2*q+1], a); a = fmaf(w.w, p2F1[2*q+1], a);
            }
            own3[j] = reluf(a);
        }
        float p3F[16]; exch8(own3, p3F, sub);

        // ---- p4 ----
        float own4[8];
#pragma unroll
        for (int j = 0; j < 8; ++j) {
            float a = pc4bS[j];
#pragma unroll
            for (int q = 0; q < 4; ++q) {
                float4 w = *reinterpret_cast<const float4*>(pc4wS + j*16 + 4*q);
                a = fmaf(w.x, p3F[4*q+0], a); a = fmaf(w.y, p3F[4*q+1], a);
                a = fmaf(w.z, p3F[4*q+2], a); a = fmaf(w.w, p3F[4*q+3], a);
            }
            own4[j] = reluf(a);
        }
        float p4F[16]; exch8(own4, p4F, sub);

        // ---- p5 accumulate (own half only) ----
#pragma unroll
        for (int j = 0; j < 8; ++j) {
            float a = p5a[j];
#pragma unroll
            for (int q = 0; q < 4; ++q) {
                float4 w = *reinterpret_cast<const float4*>(pc5sS + g*256 + j*16 + 4*q);
                a = fmaf(w.x, p4F[4*q+0], a); a = fmaf(w.y, p4F[4*q+1], a);
                a = fmaf(w.z, p4F[4*q+2], a); a = fmaf(w.w, p4F[4*q+3], a);
            }
            p5a[j] = a;
        }
    }

    // ---- pl ----
    float p5ro[8];
#pragma unroll
    for (int j = 0; j < 8; ++j) p5ro[j] = reluf(p5a[j]);
    float p5rF[16]; exch8(p5ro, p5rF, sub);
    float hhOwn[8];
#pragma unroll
    for (int j = 0; j < 8; ++j) {
        float a = plbS[j];
#pragma unroll
        for (int q = 0; q < 4; ++q) {
            float4 w = *reinterpret_cast<const float4*>(plwS + j*16 + 4*q);
            a = fmaf(w.x, p5rF[4*q+0], a); a = fmaf(w.y, p5rF[4*q+1], a);
            a = fmaf(w.z, p5rF[4*q+2], a); a = fmaf(w.w, p5rF[4*q+3], a);
        }
        hhOwn[j] = a;
    }

    // ---- equalizer on own 4 complex symbols ----
    float trOwn[8];
#pragma unroll
    for (int m = 0; m < 4; ++m) {
        float a = crOwn[2*m], b = crOwn[2*m+1];
        float c = hhOwn[2*m], d = hhOwn[2*m+1];
        float inv = 1.0f / (c*c + d*d);
        trOwn[2*m]   = (a*c + b*d) * inv;
        trOwn[2*m+1] = (b*c - a*d) * inv;
    }
    {
        float4* op = reinterpret_cast<float4*>(crt + (size_t)i * 16 + sub * 8);
        op[0] = make_float4(trOwn[0], trOwn[1], trOwn[2], trOwn[3]);
        op[1] = make_float4(trOwn[4], trOwn[5], trOwn[6], trOwn[7]);
    }
}

// ---------------- k4s: 2 threads/element. d-convs + dl1/dl2/dl3 ----------------
__global__ __launch_bounds__(256) void k4s(const float* __restrict__ trt,
    const float* __restrict__ dc1w, const float* __restrict__ dc1b,
    const float* __restrict__ dc2w, const float* __restrict__ dc2b,
    const float* __restrict__ dc3w, const float* __restrict__ dc3b,
    const float* __restrict__ dc4w, const float* __restrict__ dc4b,
    const float* __restrict__ dl1s, const float* __restrict__ dl1b,
    const float* __restrict__ dl2w, const float* __restrict__ dl2b,
    const float* __restrict__ dl3w, const float* __restrict__ dl3b,
    float* __restrict__ out, int B)
{
    int gt  = blockIdx.x * 256 + threadIdx.x;
    int i   = gt >> 1;
    int sub = gt & 1;
    if (i >= B) return;

    const float* dc1wS = dc1w + sub * 4;
    const float* dc1bS = dc1b + sub * 4;
    const float* dc2wS = dc2w + sub * 64;   // row stride 16
    const float* dc2bS = dc2b + sub * 4;
    const float* dc3wS = dc3w + sub * 32;   // row stride 8
    const float* dc3bS = dc3b + sub * 4;
    const float* dc4wS = dc4w + sub * 32;
    const float* dc4bS = dc4b + sub * 4;
    const float* dl1sS = dl1s + sub * 64;   // [t(128)][o(8)][c]
    const float* dl1bS = dl1b + sub * 8;
    const float* dl2wS = dl2w + sub * 128;  // row stride 16
    const float* dl2bS = dl2b + sub * 8;
    const float* dl3wS = dl3w + sub * 128;
    const float* dl3bS = dl3b + sub * 8;

    float w1_[4], b1_[4];
#pragma unroll
    for (int j = 0; j < 4; ++j) { w1_[j] = dc1wS[j]; b1_[j] = dc1bS[j]; }

    float yOwn[8];
#pragma unroll
    for (int j = 0; j < 8; ++j) yOwn[j] = dl1bS[j];

#pragma unroll 1
    for (int t = 0; t < 8; ++t) {
        float2 tv = *reinterpret_cast<const float2*>(trt + (size_t)i * 16 + 2 * t);
        float d1ao[4], d1bo[4];
#pragma unroll
        for (int j = 0; j < 4; ++j) {
            d1ao[j] = reluf(fmaf(w1_[j], tv.x, b1_[j]));
            d1bo[j] = reluf(fmaf(w1_[j], tv.y, b1_[j]));
        }
        float d1aF[8], d1bF[8];
        exch4(d1ao, d1aF, sub);
        exch4(d1bo, d1bF, sub);

        float d2o[4];
#pragma unroll
        for (int j = 0; j < 4; ++j) {
            float a = dc2bS[j];
#pragma unroll
            for (int q = 0; q < 4; ++q) {
                float4 w = *reinterpret_cast<const float4*>(dc2wS + j*16 + 4*q);
                a = fmaf(w.x, d1aF[2*q+0], a); a = fmaf(w.y, d1bF[2*q+0], a);
                a = fmaf(w.z, d1aF[2*q+1], a); a = fmaf(w.w, d1bF[2*q+1], a);
            }
            d2o[j] = reluf(a);
        }
        float d2F[8]; exch4(d2o, d2F, sub);

        float d3o[4];
#pragma unroll
        for (int j = 0; j < 4; ++j) {
            float a = dc3bS[j];
#pragma unroll
            for (int q = 0; q < 2; ++q) {
                float4 w = *reinterpret_cast<const float4*>(dc3wS + j*8 + 4*q);
                a = fmaf(w.x, d2F[4*q+0], a); a = fmaf(w.y, d2F[4*q+1], a);
                a = fmaf(w.z, d2F[4*q+2], a); a = fmaf(w.w, d2F[4*q+3], a);
            }
            d3o[j] = reluf(a);
        }
        float d3F[8]; exch4(d3o, d3F, sub);

        float d4o[4];
#pragma unroll
        for (int j = 0; j < 4; ++j) {
            float a = dc4bS[j];
#pragma unroll
            for (int q = 0; q < 2; ++q) {
                float4 w = *reinterpret_cast<const float4*>(dc4wS + j*8 + 4*q);
                a = fmaf(w.x, d3F[4*q+0], a); a = fmaf(w.y, d3F[4*q+1], a);
                a = fmaf(w.z, d3F[4*q+2], a); a = fmaf(w.w, d3F[4*q+3], a);
            }
            d4o[j] = reluf(a);
        }
        float d4F[8]; exch4(d4o, d4F, sub);

#pragma unroll
        for (int j = 0; j < 8; ++j) {
            float a = yOwn[j];
#pragma unroll
            for (int q = 0; q < 2; ++q) {
                float4 w = *reinterpret_cast<const float4*>(dl1sS + t*128 + j*8 + 4*q);
                a = fmaf(w.x, d4F[4*q+0], a); a = fmaf(w.y, d4F[4*q+1], a);
                a = fmaf(w.z, d4F[4*q+2], a); a = fmaf(w.w, d4F[4*q+3], a);
            }
            yOwn[j] = a;
        }
    }

#pragma unroll
    for (int j = 0; j < 8; ++j) yOwn[j] = reluf(yOwn[j]);
    float yF[16]; exch8(yOwn, yF, sub);

    float h2o[8];
#pragma unroll
    for (int j = 0; j < 8; ++j) {
        float a = dl2bS[j];
#pragma unroll
        for (int q = 0; q < 4; ++q) {
            float4 w = *reinterpret_cast<const float4*>(dl2wS + j*16 + 4*q);
            a = fmaf(w.x, yF[4*q+0], a); a = fmaf(w.y, yF[4*q+1], a);
            a = fmaf(w.z, yF[4*q+2], a); a = fmaf(w.w, yF[4*q+3], a);
        }
        h2o[j] = eluf(a);
    }
    float h2F[16]; exch8(h2o, h2F, sub);

    float oOwn[8];
#pragma unroll
    for (int j = 0; j < 8; ++j) {
        float a = dl3bS[j];
#pragma unroll
        for (int q = 0; q < 4; ++q) {
            float4 w = *reinterpret_cast<const float4*>(dl3wS + j*16 + 4*q);
            a = fmaf(w.x, h2F[4*q+0], a); a = fmaf(w.y, h2F[4*q+1], a);
            a = fmaf(w.z, h2F[4*q+2], a); a = fmaf(w.w, h2F[4*q+3], a);
        }
        oOwn[j] = a;
    }
    {
        float4* op = reinterpret_cast<float4*>(out + (size_t)i * 16 + sub * 8);
        op[0] = make_float4(oOwn[0], oOwn[1], oOwn[2], oOwn[3]);
        op[1] = make_float4(oOwn[4], oOwn[5], oOwn[6], oOwn[7]);
    }
}

extern "C" void kernel_launch(void* const* d_in, const int* in_sizes, int n_in,
                              void* d_out, int out_size, void* d_ws, size_t ws_size,
                              hipStream_t stream)
{
    const float* x      = (const float*)d_in[0];
    const float* noise  = (const float*)d_in[1];
    const float* fading = (const float*)d_in[2];
    const float* ew1  = (const float*)d_in[3];
    const float* eb1  = (const float*)d_in[4];
    const float* ew2  = (const float*)d_in[5];
    const float* eb2  = (const float*)d_in[6];
    const float* bng  = (const float*)d_in[7];
    const float* bnb  = (const float*)d_in[8];
    const float* pc1w = (const float*)d_in[9];
    const float* pc1b = (const float*)d_in[10];
    const float* pc2w = (const float*)d_in[11];
    const float* pc2b = (const float*)d_in[12];
    const float* pc3w = (const float*)d_in[13];
    const float* pc3b = (const float*)d_in[14];
    const float* pc4w = (const float*)d_in[15];
    const float* pc4b = (const float*)d_in[16];
    const float* pc5w = (const float*)d_in[17];
    const float* pc5b = (const float*)d_in[18];
    const float* plw  = (const float*)d_in[19];
    const float* plb  = (const float*)d_in[20];
    const float* dc1w = (const float*)d_in[21];
    const float* dc1b = (const float*)d_in[22];
    const float* dc2w = (const float*)d_in[23];
    const float* dc2b = (const float*)d_in[24];
    const float* dc3w = (const float*)d_in[25];
    const float* dc3b = (const float*)d_in[26];
    const float* dc4w = (const float*)d_in[27];
    const float* dc4b = (const float*)d_in[28];
    const float* dl1w = (const float*)d_in[29];
    const float* dl1b = (const float*)d_in[30];
    const float* dl2w = (const float*)d_in[31];
    const float* dl2b = (const float*)d_in[32];
    const float* dl3w = (const float*)d_in[33];
    const float* dl3b = (const float*)d_in[34];

    int B = in_sizes[0] / 16;
    int nblk  = (B + 255) / 256;
    int nblkP = (2 * B + 255) / 256;   // pair grid: 2 threads per element

    float* partials = (float*)d_ws;                    // nblk*32
    float* bnp  = partials + (size_t)nblk * 32;        // 32
    float* pc2s = bnp + 32;                            // 512
    float* pc5s = pc2s + 512;                          // 768
    float* dl1s = pc5s + 768;                          // 1024
    float* crt  = dl1s + 1024;                         // B*16 (z -> cr -> tr in-place)

    kW<<<1, 256, 0, stream>>>(pc2w, pc5w, dl1w, pc2s, pc5s, dl1s);
    kA<<<nblk, 256, 0, stream>>>(x, ew1, eb1, ew2, eb2, partials, crt, B);
    kB<<<1, 256, 0, stream>>>(partials, nblk, B, bng, bnb, bnp);
    k23s<<<nblkP, 256, 0, stream>>>(crt, fading, noise, bnp,
                                    pc1w, pc1b, pc2s, pc2b, pc3w, pc3b, pc4w, pc4b, pc5s, pc5b,
                                    plw, plb, B);
    k4s<<<nblkP, 256, 0, stream>>>(crt,
                                   dc1w, dc1b, dc2w, dc2b, dc3w, dc3b, dc4w, dc4b,
                                   dl1s, dl1b, dl2w, dl2b, dl3w, dl3b,
                                   (float*)d_out, B);
}

// Round 9
// 525.636 us; speedup vs baseline: 4.4796x; 1.7406x over previous
//
#include <hip/hip_runtime.h>
#include <math.h>

#define NSCALE 0.44668359215096315f

__device__ __forceinline__ float eluf(float v)  { return v > 0.0f ? v : __expf(v) - 1.0f; }
__device__ __forceinline__ float reluf(float v) { return fmaxf(v, 0.0f); }

// partner-lane value via DPP quad_perm(1,0,3,2): pure VALU, no LDS pipe
__device__ __forceinline__ float xor1(float v) {
    return __int_as_float(__builtin_amdgcn_update_dpp(
        0, __float_as_int(v), 0xB1, 0xF, 0xF, true));
}

// ---------------- kW: one-time per-sub weight permutation into ws ----------------
// pF slot ci of thread sub holds channel (ci ^ (sub*half)); weights pre-permuted to match.
__global__ __launch_bounds__(256) void kW(
    const float* __restrict__ pc2w, const float* __restrict__ pc3w,
    const float* __restrict__ pc4w, const float* __restrict__ pc5w,
    const float* __restrict__ plw,
    const float* __restrict__ dc2w, const float* __restrict__ dc3w,
    const float* __restrict__ dc4w, const float* __restrict__ dl1w,
    const float* __restrict__ dl2w, const float* __restrict__ dl3w,
    float* __restrict__ pc2p, float* __restrict__ pc3p, float* __restrict__ pc4p,
    float* __restrict__ pc5p, float* __restrict__ plp,
    float* __restrict__ dc2p, float* __restrict__ dc3p, float* __restrict__ dc4p,
    float* __restrict__ dl1p, float* __restrict__ dl2p, float* __restrict__ dl3p)
{
    int tid = threadIdx.x;
    for (int n = tid; n < 512; n += 256) {   // pc2p [sub][tap][j8][ci16]
        int sub = n >> 8, tap = (n >> 7) & 1, j = (n >> 4) & 7, ci = n & 15;
        pc2p[n] = pc2w[(8*sub + j)*32 + (ci ^ (8*sub))*2 + tap];
    }
    for (int n = tid; n < 512; n += 256) {   // pc3p [sub][j8][ci16][tap2]
        int sub = n >> 8, j = (n >> 5) & 7, ci = (n >> 1) & 15, tap = n & 1;
        pc3p[n] = pc3w[(8*sub + j)*32 + (ci ^ (8*sub))*2 + tap];
    }
    for (int n = tid; n < 256; n += 256) {   // pc4p [sub][j8][ci16]
        int sub = n >> 7, j = (n >> 4) & 7, ci = n & 15;
        pc4p[n] = pc4w[(8*sub + j)*16 + (ci ^ (8*sub))];
    }
    for (int n = tid; n < 768; n += 256) {   // pc5p [sub][g3][j8][ci16]
        int sub = n / 384, r = n % 384;
        int g = r >> 7, j = (r >> 4) & 7, ci = r & 15;
        pc5p[n] = pc5w[(8*sub + j)*48 + (ci ^ (8*sub))*3 + g];
    }
    for (int n = tid; n < 256; n += 256) {   // plp [sub][j8][ci16]
        int sub = n >> 7, j = (n >> 4) & 7, ci = n & 15;
        plp[n] = plw[(8*sub + j)*16 + (ci ^ (8*sub))];
    }
    for (int n = tid; n < 128; n += 256) {   // dc2p [sub][j4][ci8][ab2]
        int sub = n >> 6, j = (n >> 4) & 3, ci = (n >> 1) & 7, ab = n & 1;
        dc2p[n] = dc2w[(4*sub + j)*16 + (ci ^ (4*sub))*2 + ab];
    }
    for (int n = tid; n < 64; n += 256) {    // dc3p [sub][j4][ci8]
        int sub = n >> 5, j = (n >> 3) & 3, ci = n & 7;
        dc3p[n] = dc3w[(4*sub + j)*8 + (ci ^ (4*sub))];
    }
    for (int n = tid; n < 64; n += 256) {    // dc4p
        int sub = n >> 5, j = (n >> 3) & 3, ci = n & 7;
        dc4p[n] = dc4w[(4*sub + j)*8 + (ci ^ (4*sub))];
    }
    for (int n = tid; n < 1024; n += 256) {  // dl1p [sub][t8][j8][ci8]
        int sub = n >> 9, t = (n >> 6) & 7, j = (n >> 3) & 7, ci = n & 7;
        dl1p[n] = dl1w[(8*sub + j)*64 + (ci ^ (4*sub))*8 + t];
    }
    for (int n = tid; n < 256; n += 256) {   // dl2p [sub][j8][ci16]
        int sub = n >> 7, j = (n >> 4) & 7, ci = n & 15;
        dl2p[n] = dl2w[(8*sub + j)*16 + (ci ^ (8*sub))];
    }
    for (int n = tid; n < 256; n += 256) {   // dl3p
        int sub = n >> 7, j = (n >> 4) & 7, ci = n & 15;
        dl3p[n] = dl3w[(8*sub + j)*16 + (ci ^ (8*sub))];
    }
}

// ---------------- kA: encoder -> z (stored to ws), per-block partial sums ----------------
__global__ __launch_bounds__(256) void kA(const float* __restrict__ x,
                                          const float* __restrict__ ew1, const float* __restrict__ eb1,
                                          const float* __restrict__ ew2, const float* __restrict__ eb2,
                                          float* __restrict__ partials, float* __restrict__ zout, int B)
{
    __shared__ float wsum[4][32];
    int tid = threadIdx.x;
    int i = blockIdx.x * 256 + tid;
    bool valid = i < B;
    float xv[16];
    if (valid) {
        const float4* xp = reinterpret_cast<const float4*>(x + (size_t)i * 16);
#pragma unroll
        for (int q = 0; q < 4; ++q) {
            float4 v = xp[q];
            xv[4*q+0] = v.x; xv[4*q+1] = v.y; xv[4*q+2] = v.z; xv[4*q+3] = v.w;
        }
    } else {
#pragma unroll
        for (int q = 0; q < 16; ++q) xv[q] = 0.0f;
    }

    float h1[16];
#pragma unroll
    for (int o = 0; o < 16; ++o) {
        float a = eb1[o];
#pragma unroll
        for (int k = 0; k < 16; ++k) a = fmaf(xv[k], ew1[o*16+k], a);
        h1[o] = eluf(a);
    }
    float z[16];
#pragma unroll
    for (int o = 0; o < 16; ++o) {
        float a = eb2[o];
#pragma unroll
        for (int k = 0; k < 16; ++k) a = fmaf(h1[k], ew2[o*16+k], a);
        z[o] = valid ? a : 0.0f;
    }

    if (valid) {
        float4* zp = reinterpret_cast<float4*>(zout + (size_t)i * 16);
        zp[0] = make_float4(z[0],  z[1],  z[2],  z[3]);
        zp[1] = make_float4(z[4],  z[5],  z[6],  z[7]);
        zp[2] = make_float4(z[8],  z[9],  z[10], z[11]);
        zp[3] = make_float4(z[12], z[13], z[14], z[15]);
    }

    int lane = tid & 63, wave = tid >> 6;
#pragma unroll
    for (int c = 0; c < 16; ++c) {
        float s = z[c];
        float q = z[c] * z[c];
#pragma unroll
        for (int m = 1; m < 64; m <<= 1) { s += __shfl_xor(s, m); q += __shfl_xor(q, m); }
        if (lane == 0) { wsum[wave][c] = s; wsum[wave][16 + c] = q; }
    }
    __syncthreads();
    if (tid < 32) {
        float t = wsum[0][tid] + wsum[1][tid] + wsum[2][tid] + wsum[3][tid];
        partials[(size_t)blockIdx.x * 32 + tid] = t;
    }
}

// ---------------- kB: reduce partials -> BN affine ----------------
__global__ __launch_bounds__(256) void kB(const float* __restrict__ partials, int nblk, int B,
                                          const float* __restrict__ bng, const float* __restrict__ bnb,
                                          float* __restrict__ bnp)
{
    int tid = threadIdx.x;
    int q = tid >> 3, k = tid & 7;
    int chunk = (nblk + 7) / 8;
    int j0 = k * chunk;
    int j1 = j0 + chunk; if (j1 > nblk) j1 = nblk;
    double s = 0.0;
    for (int j = j0; j < j1; ++j) s += (double)partials[(size_t)j * 32 + q];
    s += __shfl_xor(s, 4);
    s += __shfl_xor(s, 2);
    s += __shfl_xor(s, 1);
    __shared__ double tot[32];
    if (k == 0) tot[q] = s;
    __syncthreads();
    if (tid < 16) {
        double mu  = tot[tid] / (double)B;
        double var = tot[16 + tid] / (double)B - mu * mu;
        double a = (double)bng[tid] / sqrt(var + 1e-5);
        double b = (double)bnb[tid] - mu * a;
        bnp[tid]      = (float)a;
        bnp[16 + tid] = (float)b;
    }
}

// p1 own rows for column COL, produce exchanged pF[16] for both elems
template<int COL>
__device__ __forceinline__ void p1_pf(const float* __restrict__ pc1S,
                                      const float* __restrict__ pc1bS,
                                      const float cA[8], const float cB[8],
                                      float pFA[16], float pFB[16])
{
#pragma unroll
    for (int j = 0; j < 8; ++j) {
        float4 w = *reinterpret_cast<const float4*>(pc1S + j*4);
        float b = pc1bS[j];
        float aA = b, aB = b;
        aA = fmaf(w.x, cA[COL+0], aA); aA = fmaf(w.y, cA[COL+1], aA);
        aA = fmaf(w.z, cA[COL+2], aA); aA = fmaf(w.w, cA[COL+3], aA);
        aB = fmaf(w.x, cB[COL+0], aB); aB = fmaf(w.y, cB[COL+1], aB);
        aB = fmaf(w.z, cB[COL+2], aB); aB = fmaf(w.w, cB[COL+3], aB);
        float rA = reluf(aA), rB = reluf(aB);
        pFA[j] = rA; pFA[8+j] = xor1(rA);
        pFB[j] = rB; pFB[8+j] = xor1(rB);
    }
}

// 8-row x 16-input accumulate for both elems (weights contiguous per row)
__device__ __forceinline__ void acc16(const float* __restrict__ wbase,
                                      const float pFA[16], const float pFB[16],
                                      float qA[8], float qB[8])
{
#pragma unroll
    for (int j = 0; j < 8; ++j) {
        float aA = qA[j], aB = qB[j];
#pragma unroll
        for (int q = 0; q < 4; ++q) {
            float4 w = *reinterpret_cast<const float4*>(wbase + j*16 + 4*q);
            aA = fmaf(w.x, pFA[4*q+0], aA); aA = fmaf(w.y, pFA[4*q+1], aA);
            aA = fmaf(w.z, pFA[4*q+2], aA); aA = fmaf(w.w, pFA[4*q+3], aA);
            aB = fmaf(w.x, pFB[4*q+0], aB); aB = fmaf(w.y, pFB[4*q+1], aB);
            aB = fmaf(w.z, pFB[4*q+2], aB); aB = fmaf(w.w, pFB[4*q+3], aB);
        }
        qA[j] = aA; qB[j] = aB;
    }
}

// ---------------- k23s: pair-split (2 elems x half channels per thread) ----------------
__global__ __launch_bounds__(256) void k23s(float* __restrict__ crt,
    const float* __restrict__ fading, const float* __restrict__ noise,
    const float* __restrict__ bnp,
    const float* __restrict__ pc1w, const float* __restrict__ pc1b,
    const float* __restrict__ pc2p, const float* __restrict__ pc2b,
    const float* __restrict__ pc3p, const float* __restrict__ pc3b,
    const float* __restrict__ pc4p, const float* __restrict__ pc4b,
    const float* __restrict__ pc5p, const float* __restrict__ pc5b,
    const float* __restrict__ plp,  const float* __restrict__ plb,
    int B)
{
    int gt = blockIdx.x * 256 + threadIdx.x;
    if (gt >= B) return;
    int sub = gt & 1;
    int e0 = gt & ~1;
    int e1 = e0 + 1; if (e1 >= B) e1 = e0;

    // ---- head: BN + FIR + noise for both elems (dup across pair), store cr ----
#pragma unroll 1
    for (int it = 0; it < 2; ++it) {
        if (it && e1 == e0) break;
        int e = it ? e1 : e0;
        float zn[16];
        {
            const float4* zp = reinterpret_cast<const float4*>(crt + (size_t)e * 16);
#pragma unroll
            for (int q = 0; q < 4; ++q) {
                float4 v = zp[q];
                zn[4*q+0] = fmaf(v.x, bnp[4*q+0], bnp[16 + 4*q+0]);
                zn[4*q+1] = fmaf(v.y, bnp[4*q+1], bnp[16 + 4*q+1]);
                zn[4*q+2] = fmaf(v.z, bnp[4*q+2], bnp[16 + 4*q+2]);
                zn[4*q+3] = fmaf(v.w, bnp[4*q+3], bnp[16 + 4*q+3]);
            }
        }
        float f[6];
        {
            const float2* fp = reinterpret_cast<const float2*>(fading + (size_t)e * 6);
#pragma unroll
            for (int q = 0; q < 3; ++q) { float2 v = fp[q]; f[2*q] = v.x; f[2*q+1] = v.y; }
        }
        float cr[16];
#pragma unroll
        for (int n = 0; n < 8; ++n) {
            float re = f[0]*zn[2*n]   - f[1]*zn[2*n+1];
            float im = f[0]*zn[2*n+1] + f[1]*zn[2*n];
            if (n >= 1) { re += f[2]*zn[2*n-2] - f[3]*zn[2*n-1];
                          im += f[2]*zn[2*n-1] + f[3]*zn[2*n-2]; }
            if (n >= 2) { re += f[4]*zn[2*n-4] - f[5]*zn[2*n-3];
                          im += f[4]*zn[2*n-3] + f[5]*zn[2*n-4]; }
            cr[2*n] = re; cr[2*n+1] = im;
        }
        {
            const float4* np_ = reinterpret_cast<const float4*>(noise + (size_t)e * 16);
#pragma unroll
            for (int q = 0; q < 4; ++q) {
                float4 v = np_[q];
                cr[4*q+0] = fmaf(v.x, NSCALE, cr[4*q+0]);
                cr[4*q+1] = fmaf(v.y, NSCALE, cr[4*q+1]);
                cr[4*q+2] = fmaf(v.z, NSCALE, cr[4*q+2]);
                cr[4*q+3] = fmaf(v.w, NSCALE, cr[4*q+3]);
            }
        }
        float4* op = reinterpret_cast<float4*>(crt + (size_t)e * 16);
        op[0] = make_float4(cr[0],  cr[1],  cr[2],  cr[3]);
        op[1] = make_float4(cr[4],  cr[5],  cr[6],  cr[7]);
        op[2] = make_float4(cr[8],  cr[9],  cr[10], cr[11]);
        op[3] = make_float4(cr[12], cr[13], cr[14], cr[15]);
    }

    // ---- per-sub weight bases ----
    const float* pc1S  = pc1w + sub*32;
    const float* pc1bS = pc1b + sub*8;
    const float* pc2S  = pc2p + sub*256;   // + tap*128 + j*16 + ci
    const float* pc2bS = pc2b + sub*8;
    const float* pc3S  = pc3p + sub*256;   // + j*32 + ci*2 + tap
    const float* pc3bS = pc3b + sub*8;
    const float* pc4S  = pc4p + sub*128;   // + j*16 + ci
    const float* pc4bS = pc4b + sub*8;
    const float* pc5S  = pc5p + sub*384;   // + g*128 + j*16 + ci
    const float* pc5bS = pc5b + sub*8;
    const float* plS   = plp  + sub*128;
    const float* plbS  = plb  + sub*8;

    float p5aA[8], p5aB[8];
#pragma unroll
    for (int j = 0; j < 8; ++j) { float b = pc5bS[j]; p5aA[j] = b; p5aB[j] = b; }

#pragma unroll 1
    for (int g = 0; g < 3; ++g) {
        float cA[8], cB[8];
        {
            const float4* pa = reinterpret_cast<const float4*>(crt + (size_t)e0 * 16 + 4 * g);
            float4 a0 = pa[0], a1 = pa[1];
            cA[0]=a0.x; cA[1]=a0.y; cA[2]=a0.z; cA[3]=a0.w;
            cA[4]=a1.x; cA[5]=a1.y; cA[6]=a1.z; cA[7]=a1.w;
            const float4* pb = reinterpret_cast<const float4*>(crt + (size_t)e1 * 16 + 4 * g);
            float4 b0 = pb[0], b1 = pb[1];
            cB[0]=b0.x; cB[1]=b0.y; cB[2]=b0.z; cB[3]=b0.w;
            cB[4]=b1.x; cB[5]=b1.y; cB[6]=b1.z; cB[7]=b1.w;
        }
        float q0A[8], q1A[8], q0B[8], q1B[8];
#pragma unroll
        for (int j = 0; j < 8; ++j) { float b = pc2bS[j]; q0A[j]=b; q1A[j]=b; q0B[j]=b; q1B[j]=b; }

        {   // t-step 0: q0 += tap0 * p1(col0)
            float pFA[16], pFB[16];
            p1_pf<0>(pc1S, pc1bS, cA, cB, pFA, pFB);
            acc16(pc2S, pFA, pFB, q0A, q0B);
        }
        {   // t-step 1: q1 += tap0 * p1(col1); q0 += tap1 * p1(col1)
            float pFA[16], pFB[16];
            p1_pf<1>(pc1S, pc1bS, cA, cB, pFA, pFB);
            acc16(pc2S,       pFA, pFB, q1A, q1B);
            acc16(pc2S + 128, pFA, pFB, q0A, q0B);
        }
        {   // t-step 2: q1 += tap1 * p1(col2)
            float pFA[16], pFB[16];
            p1_pf<2>(pc1S, pc1bS, cA, cB, pFA, pFB);
            acc16(pc2S + 128, pFA, pFB, q1A, q1B);
        }

        // relu + exchange q -> full 16 (pF order)
        float q0FA[16], q1FA[16], q0FB[16], q1FB[16];
#pragma unroll
        for (int j = 0; j < 8; ++j) {
            float r0A = reluf(q0A[j]); q0FA[j] = r0A; q0FA[8+j] = xor1(r0A);
            float r1A = reluf(q1A[j]); q1FA[j] = r1A; q1FA[8+j] = xor1(r1A);
            float r0B = reluf(q0B[j]); q0FB[j] = r0B; q0FB[8+j] = xor1(r0B);
            float r1B = reluf(q1B[j]); q1FB[j] = r1B; q1FB[8+j] = xor1(r1B);
        }

        // p3: [j][ci][tap] layout; f4 = (ci,t0),(ci,t1),(ci+1,t0),(ci+1,t1)
        float p3FA[16], p3FB[16];
#pragma unroll
        for (int j = 0; j < 8; ++j) {
            float aA = pc3bS[j], aB = aA;
#pragma unroll
            for (int q = 0; q < 8; ++q) {
                float4 w = *reinterpret_cast<const float4*>(pc3S + j*32 + 4*q);
                aA = fmaf(w.x, q0FA[2*q+0], aA); aA = fmaf(w.y, q1FA[2*q+0], aA);
                aA = fmaf(w.z, q0FA[2*q+1], aA); aA = fmaf(w.w, q1FA[2*q+1], aA);
                aB = fmaf(w.x, q0FB[2*q+0], aB); aB = fmaf(w.y, q1FB[2*q+0], aB);
                aB = fmaf(w.z, q0FB[2*q+1], aB); aB = fmaf(w.w, q1FB[2*q+1], aB);
            }
            float rA = reluf(aA), rB = reluf(aB);
            p3FA[j] = rA; p3FA[8+j] = xor1(rA);
            p3FB[j] = rB; p3FB[8+j] = xor1(rB);
        }

        // p4
        float p4FA[16], p4FB[16];
#pragma unroll
        for (int j = 0; j < 8; ++j) {
            float aA = pc4bS[j], aB = aA;
#pragma unroll
            for (int q = 0; q < 4; ++q) {
                float4 w = *reinterpret_cast<const float4*>(pc4S + j*16 + 4*q);
                aA = fmaf(w.x, p3FA[4*q+0], aA); aA = fmaf(w.y, p3FA[4*q+1], aA);
                aA = fmaf(w.z, p3FA[4*q+2], aA); aA = fmaf(w.w, p3FA[4*q+3], aA);
                aB = fmaf(w.x, p3FB[4*q+0], aB); aB = fmaf(w.y, p3FB[4*q+1], aB);
                aB = fmaf(w.z, p3FB[4*q+2], aB); aB = fmaf(w.w, p3FB[4*q+3], aB);
            }
            float rA = reluf(aA), rB = reluf(aB);
            p4FA[j] = rA; p4FA[8+j] = xor1(rA);
            p4FB[j] = rB; p4FB[8+j] = xor1(rB);
        }

        // p5 accumulate (own rows only)
#pragma unroll
        for (int j = 0; j < 8; ++j) {
            float aA = p5aA[j], aB = p5aB[j];
#pragma unroll
            for (int q = 0; q < 4; ++q) {
                float4 w = *reinterpret_cast<const float4*>(pc5S + g*128 + j*16 + 4*q);
                aA = fmaf(w.x, p4FA[4*q+0], aA); aA = fmaf(w.y, p4FA[4*q+1], aA);
                aA = fmaf(w.z, p4FA[4*q+2], aA); aA = fmaf(w.w, p4FA[4*q+3], aA);
                aB = fmaf(w.x, p4FB[4*q+0], aB); aB = fmaf(w.y, p4FB[4*q+1], aB);
                aB = fmaf(w.z, p4FB[4*q+2], aB); aB = fmaf(w.w, p4FB[4*q+3], aB);
            }
            p5aA[j] = aA; p5aB[j] = aB;
        }
    }

    // pl
    float p5FA[16], p5FB[16];
#pragma unroll
    for (int j = 0; j < 8; ++j) {
        float rA = reluf(p5aA[j]); p5FA[j] = rA; p5FA[8+j] = xor1(rA);
        float rB = reluf(p5aB[j]); p5FB[j] = rB; p5FB[8+j] = xor1(rB);
    }
    float hhA[8], hhB[8];
#pragma unroll
    for (int j = 0; j < 8; ++j) {
        float aA = plbS[j], aB = aA;
#pragma unroll
        for (int q = 0; q < 4; ++q) {
            float4 w = *reinterpret_cast<const float4*>(plS + j*16 + 4*q);
            aA = fmaf(w.x, p5FA[4*q+0], aA); aA = fmaf(w.y, p5FA[4*q+1], aA);
            aA = fmaf(w.z, p5FA[4*q+2], aA); aA = fmaf(w.w, p5FA[4*q+3], aA);
            aB = fmaf(w.x, p5FB[4*q+0], aB); aB = fmaf(w.y, p5FB[4*q+1], aB);
            aB = fmaf(w.z, p5FB[4*q+2], aB); aB = fmaf(w.w, p5FB[4*q+3], aB);
        }
        hhA[j] = aA; hhB[j] = aB;
    }

    // equalizer on own symbol range (channels sub*8..sub*8+7 = symbols sub*4..sub*4+3)
    float crA[8], crB[8];
    {
        const float4* ca = reinterpret_cast<const float4*>(crt + (size_t)e0 * 16 + sub * 8);
        float4 a0 = ca[0], a1 = ca[1];
        crA[0]=a0.x; crA[1]=a0.y; crA[2]=a0.z; crA[3]=a0.w;
        crA[4]=a1.x; crA[5]=a1.y; crA[6]=a1.z; crA[7]=a1.w;
        const float4* cb = reinterpret_cast<const float4*>(crt + (size_t)e1 * 16 + sub * 8);
        float4 b0 = cb[0], b1 = cb[1];
        crB[0]=b0.x; crB[1]=b0.y; crB[2]=b0.z; crB[3]=b0.w;
        crB[4]=b1.x; crB[5]=b1.y; crB[6]=b1.z; crB[7]=b1.w;
    }
    float trA[8], trB[8];
#pragma unroll
    for (int m = 0; m < 4; ++m) {
        {
            float a = crA[2*m], b = crA[2*m+1];
            float c = hhA[2*m], d = hhA[2*m+1];
            float inv = 1.0f / (c*c + d*d);
            trA[2*m]   = (a*c + b*d) * inv;
            trA[2*m+1] = (b*c - a*d) * inv;
        }
        {
            float a = crB[2*m], b = crB[2*m+1];
            float c = hhB[2*m], d = hhB[2*m+1];
            float inv = 1.0f / (c*c + d*d);
            trB[2*m]   = (a*c + b*d) * inv;
            trB[2*m+1] = (b*c - a*d) * inv;
        }
    }
    {
        float4* oa = reinterpret_cast<float4*>(crt + (size_t)e0 * 16 + sub * 8);
        oa[0] = make_float4(trA[0], trA[1], trA[2], trA[3]);
        oa[1] = make_float4(trA[4], trA[5], trA[6], trA[7]);
        float4* ob = reinterpret_cast<float4*>(crt + (size_t)e1 * 16 + sub * 8);
        ob[0] = make_float4(trB[0], trB[1], trB[2], trB[3]);
        ob[1] = make_float4(trB[4], trB[5], trB[6], trB[7]);
    }
}

// ---------------- k4s: pair-split d-convs + dl1/dl2/dl3 ----------------
__global__ __launch_bounds__(256) void k4s(const float* __restrict__ trt,
    const float* __restrict__ dc1w, const float* __restrict__ dc1b,
    const float* __restrict__ dc2p, const float* __restrict__ dc2b,
    const float* __restrict__ dc3p, const float* __restrict__ dc3b,
    const float* __restrict__ dc4p, const float* __restrict__ dc4b,
    const float* __restrict__ dl1p, const float* __restrict__ dl1b,
    const float* __restrict__ dl2p, const float* __restrict__ dl2b,
    const float* __restrict__ dl3p, const float* __restrict__ dl3b,
    float* __restrict__ out, int B)
{
    int gt = blockIdx.x * 256 + threadIdx.x;
    if (gt >= B) return;
    int sub = gt & 1;
    int e0 = gt & ~1;
    int e1 = e0 + 1; if (e1 >= B) e1 = e0;

    const float* dc1wS = dc1w + sub*4;
    const float* dc1bS = dc1b + sub*4;
    const float* dc2S  = dc2p + sub*64;    // + j*16 + ci*2 + ab
    const float* dc2bS = dc2b + sub*4;
    const float* dc3S  = dc3p + sub*32;    // + j*8 + ci
    const float* dc3bS = dc3b + sub*4;
    const float* dc4S  = dc4p + sub*32;
    const float* dc4bS = dc4b + sub*4;
    const float* dl1S  = dl1p + sub*512;   // + t*64 + j*8 + ci
    const float* dl1bS = dl1b + sub*8;
    const float* dl2S  = dl2p + sub*128;   // + j*16 + ci
    const float* dl2bS = dl2b + sub*8;
    const float* dl3S  = dl3p + sub*128;
    const float* dl3bS = dl3b + sub*8;

    float w1_[4], b1_[4];
#pragma unroll
    for (int j = 0; j < 4; ++j) { w1_[j] = dc1wS[j]; b1_[j] = dc1bS[j]; }

    float yA[8], yB[8];
#pragma unroll
    for (int j = 0; j < 8; ++j) { float b = dl1bS[j]; yA[j] = b; yB[j] = b; }

#pragma unroll 1
    for (int t = 0; t < 8; ++t) {
        float2 tvA = *reinterpret_cast<const float2*>(trt + (size_t)e0 * 16 + 2 * t);
        float2 tvB = *reinterpret_cast<const float2*>(trt + (size_t)e1 * 16 + 2 * t);

        float d1aFA[8], d1bFA[8], d1aFB[8], d1bFB[8];
#pragma unroll
        for (int j = 0; j < 4; ++j) {
            float raA = reluf(fmaf(w1_[j], tvA.x, b1_[j]));
            float rbA = reluf(fmaf(w1_[j], tvA.y, b1_[j]));
            float raB = reluf(fmaf(w1_[j], tvB.x, b1_[j]));
            float rbB = reluf(fmaf(w1_[j], tvB.y, b1_[j]));
            d1aFA[j] = raA; d1aFA[4+j] = xor1(raA);
            d1bFA[j] = rbA; d1bFA[4+j] = xor1(rbA);
            d1aFB[j] = raB; d1aFB[4+j] = xor1(raB);
            d1bFB[j] = rbB; d1bFB[4+j] = xor1(rbB);
        }

        float d2FA[8], d2FB[8];
#pragma unroll
        for (int j = 0; j < 4; ++j) {
            float aA = dc2bS[j], aB = aA;
#pragma unroll
            for (int q = 0; q < 4; ++q) {
                float4 w = *reinterpret_cast<const float4*>(dc2S + j*16 + 4*q);
                aA = fmaf(w.x, d1aFA[2*q+0], aA); aA = fmaf(w.y, d1bFA[2*q+0], aA);
                aA = fmaf(w.z, d1aFA[2*q+1], aA); aA = fmaf(w.w, d1bFA[2*q+1], aA);
                aB = fmaf(w.x, d1aFB[2*q+0], aB); aB = fmaf(w.y, d1bFB[2*q+0], aB);
                aB = fmaf(w.z, d1aFB[2*q+1], aB); aB = fmaf(w.w, d1bFB[2*q+1], aB);
            }
            float rA = reluf(aA), rB = reluf(aB);
            d2FA[j] = rA; d2FA[4+j] = xor1(rA);
            d2FB[j] = rB; d2FB[4+j] = xor1(rB);
        }

        float d3FA[8], d3FB[8];
#pragma unroll
        for (int j = 0; j < 4; ++j) {
            float aA = dc3bS[j], aB = aA;
#pragma unroll
            for (int q = 0; q < 2; ++q) {
                float4 w = *reinterpret_cast<const float4*>(dc3S + j*8 + 4*q);
                aA = fmaf(w.x, d2FA[4*q+0], aA); aA = fmaf(w.y, d2FA[4*q+1], aA);
                aA = fmaf(w.z, d2FA[4*q+2], aA); aA = fmaf(w.w, d2FA[4*q+3], aA);
                aB = fmaf(w.x, d2FB[4*q+0], aB); aB = fmaf(w.y, d2FB[4*q+1], aB);
                aB = fmaf(w.z, d2FB[4*q+2], aB); aB = fmaf(w.w, d2FB[4*q+3], aB);
            }
            float rA = reluf(aA), rB = reluf(aB);
            d3FA[j] = rA; d3FA[4+j] = xor1(rA);
            d3FB[j] = rB; d3FB[4+j] = xor1(rB);
        }

        float d4FA[8], d4FB[8];
#pragma unroll
        for (int j = 0; j < 4; ++j) {
            float aA = dc4bS[j], aB = aA;
#pragma unroll
            for (int q = 0; q < 2; ++q) {
                float4 w = *reinterpret_cast<const float4*>(dc4S + j*8 + 4*q);
                aA = fmaf(w.x, d3FA[4*q+0], aA); aA = fmaf(w.y, d3FA[4*q+1], aA);
                aA = fmaf(w.z, d3FA[4*q+2], aA); aA = fmaf(w.w, d3FA[4*q+3], aA);
                aB = fmaf(w.x, d3FB[4*q+0], aB); aB = fmaf(w.y, d3FB[4*q+1], aB);
                aB = fmaf(w.z, d3FB[4*q+2], aB); aB = fmaf(w.w, d3FB[4*q+3], aB);
            }
            float rA = reluf(aA), rB = reluf(aB);
            d4FA[j] = rA; d4FA[4+j] = xor1(rA);
            d4FB[j] = rB; d4FB[4+j] = xor1(rB);
        }

#pragma unroll
        for (int j = 0; j < 8; ++j) {
            float aA = yA[j], aB = yB[j];
#pragma unroll
            for (int q = 0; q < 2; ++q) {
                float4 w = *reinterpret_cast<const float4*>(dl1S + t*64 + j*8 + 4*q);
                aA = fmaf(w.x, d4FA[4*q+0], aA); aA = fmaf(w.y, d4FA[4*q+1], aA);
                aA = fmaf(w.z, d4FA[4*q+2], aA); aA = fmaf(w.w, d4FA[4*q+3], aA);
                aB = fmaf(w.x, d4FB[4*q+0], aB); aB = fmaf(w.y, d4FB[4*q+1], aB);
                aB = fmaf(w.z, d4FB[4*q+2], aB); aB = fmaf(w.w, d4FB[4*q+3], aB);
            }
            yA[j] = aA; yB[j] = aB;
        }
    }

    float yFA[16], yFB[16];
#pragma unroll
    for (int j = 0; j < 8; ++j) {
        float rA = reluf(yA[j]); yFA[j] = rA; yFA[8+j] = xor1(rA);
        float rB = reluf(yB[j]); yFB[j] = rB; yFB[8+j] = xor1(rB);
    }

    float h2FA[16], h2FB[16];
#pragma unroll
    for (int j = 0; j < 8; ++j) {
        float aA = dl2bS[j], aB = aA;
#pragma unroll
        for (int q = 0; q < 4; ++q) {
            float4 w = *reinterpret_cast<const float4*>(dl2S + j*16 + 4*q);
            aA = fmaf(w.x, yFA[4*q+0], aA); aA = fmaf(w.y, yFA[4*q+1], aA);
            aA = fmaf(w.z, yFA[4*q+2], aA); aA = fmaf(w.w, yFA[4*q+3], aA);
            aB = fmaf(w.x, yFB[4*q+0], aB); aB = fmaf(w.y, yFB[4*q+1], aB);
            aB = fmaf(w.z, yFB[4*q+2], aB); aB = fmaf(w.w, yFB[4*q+3], aB);
        }
        float rA = eluf(aA), rB = eluf(aB);
        h2FA[j] = rA; h2FA[8+j] = xor1(rA);
        h2FB[j] = rB; h2FB[8+j] = xor1(rB);
    }

    float oA[8], oB[8];
#pragma unroll
    for (int j = 0; j < 8; ++j) {
        float aA = dl3bS[j], aB = aA;
#pragma unroll
        for (int q = 0; q < 4; ++q) {
            float4 w = *reinterpret_cast<const float4*>(dl3S + j*16 + 4*q);
            aA = fmaf(w.x, h2FA[4*q+0], aA); aA = fmaf(w.y, h2FA[4*q+1], aA);
            aA = fmaf(w.z, h2FA[4*q+2], aA); aA = fmaf(w.w, h2FA[4*q+3], aA);
            aB = fmaf(w.x, h2FB[4*q+0], aB); aB = fmaf(w.y, h2FB[4*q+1], aB);
            aB = fmaf(w.z, h2FB[4*q+2], aB); aB = fmaf(w.w, h2FB[4*q+3], aB);
        }
        oA[j] = aA; oB[j] = aB;
    }
    {
        float4* pa = reinterpret_cast<float4*>(out + (size_t)e0 * 16 + sub * 8);
        pa[0] = make_float4(oA[0], oA[1], oA[2], oA[3]);
        pa[1] = make_float4(oA[4], oA[5], oA[6], oA[7]);
        float4* pb = reinterpret_cast<float4*>(out + (size_t)e1 * 16 + sub * 8);
        pb[0] = make_float4(oB[0], oB[1], oB[2], oB[3]);
        pb[1] = make_float4(oB[4], oB[5], oB[6], oB[7]);
    }
}

extern "C" void kernel_launch(void* const* d_in, const int* in_sizes, int n_in,
                              void* d_out, int out_size, void* d_ws, size_t ws_size,
                              hipStream_t stream)
{
    const float* x      = (const float*)d_in[0];
    const float* noise  = (const float*)d_in[1];
    const float* fading = (const float*)d_in[2];
    const float* ew1  = (const float*)d_in[3];
    const float* eb1  = (const float*)d_in[4];
    const float* ew2  = (const float*)d_in[5];
    const float* eb2  = (const float*)d_in[6];
    const float* bng  = (const float*)d_in[7];
    const float* bnb  = (const float*)d_in[8];
    const float* pc1w = (const float*)d_in[9];
    const float* pc1b = (const float*)d_in[10];
    const float* pc2w = (const float*)d_in[11];
    const float* pc2b = (const float*)d_in[12];
    const float* pc3w = (const float*)d_in[13];
    const float* pc3b = (const float*)d_in[14];
    const float* pc4w = (const float*)d_in[15];
    const float* pc4b = (const float*)d_in[16];
    const float* pc5w = (const float*)d_in[17];
    const float* pc5b = (const float*)d_in[18];
    const float* plw  = (const float*)d_in[19];
    const float* plb  = (const float*)d_in[20];
    const float* dc1w = (const float*)d_in[21];
    const float* dc1b = (const float*)d_in[22];
    const float* dc2w = (const float*)d_in[23];
    const float* dc2b = (const float*)d_in[24];
    const float* dc3w = (const float*)d_in[25];
    const float* dc3b = (const float*)d_in[26];
    const float* dc4w = (const float*)d_in[27];
    const float* dc4b = (const float*)d_in[28];
    const float* dl1w = (const float*)d_in[29];
    const float* dl1b = (const float*)d_in[30];
    const float* dl2w = (const float*)d_in[31];
    const float* dl2b = (const float*)d_in[32];
    const float* dl3w = (const float*)d_in[33];
    const float* dl3b = (const float*)d_in[34];

    int B = in_sizes[0] / 16;
    int nblk = (B + 255) / 256;

    float* partials = (float*)d_ws;                    // nblk*32
    float* bnp  = partials + (size_t)nblk * 32;        // 32
    float* wsw  = bnp + 32;                            // 4096 swizzled weights
    float* pc2p = wsw;            // 512
    float* pc3p = wsw + 512;      // 512
    float* pc4p = wsw + 1024;     // 256
    float* pc5p = wsw + 1280;     // 768
    float* plp  = wsw + 2048;     // 256
    float* dc2p = wsw + 2304;     // 128
    float* dc3p = wsw + 2432;     // 64
    float* dc4p = wsw + 2496;     // 64
    float* dl1p = wsw + 2560;     // 1024
    float* dl2p = wsw + 3584;     // 256
    float* dl3p = wsw + 3840;     // 256
    float* crt  = wsw + 4096;     // B*16 (z -> cr -> tr in-place)

    kW<<<1, 256, 0, stream>>>(pc2w, pc3w, pc4w, pc5w, plw,
                              dc2w, dc3w, dc4w, dl1w, dl2w, dl3w,
                              pc2p, pc3p, pc4p, pc5p, plp,
                              dc2p, dc3p, dc4p, dl1p, dl2p, dl3p);
    kA<<<nblk, 256, 0, stream>>>(x, ew1, eb1, ew2, eb2, partials, crt, B);
    kB<<<1, 256, 0, stream>>>(partials, nblk, B, bng, bnb, bnp);
    k23s<<<nblk, 256, 0, stream>>>(crt, fading, noise, bnp,
                                   pc1w, pc1b, pc2p, pc2b, pc3p, pc3b, pc4p, pc4b, pc5p, pc5b,
                                   plp, plb, B);
    k4s<<<nblk, 256, 0, stream>>>(crt,
                                  dc1w, dc1b, dc2p, dc2b, dc3p, dc3b, dc4p, dc4b,
                                  dl1p, dl1b, dl2p, dl2b, dl3p, dl3b,
                                  (float*)d_out, B);
}

// Round 10
// 227.838 us; speedup vs baseline: 10.3347x; 2.3071x over previous
//
#include <hip/hip_runtime.h>
#include <math.h>

#define NSCALE 0.44668359215096315f

typedef float v2f __attribute__((ext_vector_type(2)));

__device__ __forceinline__ v2f fma2(v2f a, v2f b, v2f c) { return __builtin_elementwise_fma(a, b, c); }
__device__ __forceinline__ float eluf(float v)  { return v > 0.0f ? v : __expf(v) - 1.0f; }
__device__ __forceinline__ float reluf(float v) { return fmaxf(v, 0.0f); }

// packed dot helpers: weights contiguous, inputs pre-paired, acc float2 + horizontal add
__device__ __forceinline__ float dot16p(const float* __restrict__ w, const v2f p[8], float b) {
    const v2f* w2 = reinterpret_cast<const v2f*>(w);
    v2f a = {b, 0.0f};
#pragma unroll
    for (int q = 0; q < 8; ++q) a = fma2(w2[q], p[q], a);
    return a.x + a.y;
}
__device__ __forceinline__ float dot32p(const float* __restrict__ w, const v2f p[16], float b) {
    const v2f* w2 = reinterpret_cast<const v2f*>(w);
    v2f a = {b, 0.0f};
#pragma unroll
    for (int q = 0; q < 16; ++q) a = fma2(w2[q], p[q], a);
    return a.x + a.y;
}
__device__ __forceinline__ float dot8p(const float* __restrict__ w, const v2f p[4], float b) {
    const v2f* w2 = reinterpret_cast<const v2f*>(w);
    v2f a = {b, 0.0f};
#pragma unroll
    for (int q = 0; q < 4; ++q) a = fma2(w2[q], p[q], a);
    return a.x + a.y;
}

// ---------------- kW: one-time weight swizzle (consumption-order layouts) ----------------
__global__ __launch_bounds__(256) void kW(const float* __restrict__ pc2w,
                                          const float* __restrict__ pc5w,
                                          const float* __restrict__ dl1w,
                                          float* __restrict__ pc2s,
                                          float* __restrict__ pc5s,
                                          float* __restrict__ dl1s)
{
    int tid = threadIdx.x;
    for (int j = tid; j < 512; j += 256) {            // pc2w[o*32+ci*2+tap] -> [tap][o][ci]
        int o = j >> 5, r = j & 31, ci = r >> 1, tap = r & 1;
        pc2s[tap*256 + o*16 + ci] = pc2w[j];
    }
    for (int j = tid; j < 768; j += 256) {            // pc5w[o*48+ci*3+g] -> [g][o][ci]
        int o = j / 48, r = j - o*48, ci = r / 3, g = r - ci*3;
        pc5s[g*256 + o*16 + ci] = pc5w[j];
    }
    for (int j = tid; j < 1024; j += 256) {           // dl1w[o*64+c*8+t] -> [t][o][c]
        int o = j >> 6, r = j & 63, c = r >> 3, t = r & 7;
        dl1s[t*128 + o*8 + c] = dl1w[j];
    }
}

// ---------------- kA: encoder -> z (stored to ws), per-block partial sums ----------------
__global__ __launch_bounds__(256) void kA(const float* __restrict__ x,
                                          const float* __restrict__ ew1, const float* __restrict__ eb1,
                                          const float* __restrict__ ew2, const float* __restrict__ eb2,
                                          float* __restrict__ partials, float* __restrict__ zout, int B)
{
    __shared__ float wsum[4][32];
    int tid = threadIdx.x;
    int i = blockIdx.x * 256 + tid;
    bool valid = i < B;
    v2f x2[8];
    if (valid) {
        const float4* xp = reinterpret_cast<const float4*>(x + (size_t)i * 16);
#pragma unroll
        for (int q = 0; q < 4; ++q) {
            float4 v = xp[q];
            x2[2*q+0] = {v.x, v.y};
            x2[2*q+1] = {v.z, v.w};
        }
    } else {
#pragma unroll
        for (int q = 0; q < 8; ++q) x2[q] = {0.0f, 0.0f};
    }

    v2f h1p[8];
#pragma unroll
    for (int j = 0; j < 8; ++j) {
        float r0 = eluf(dot16p(ew1 + (2*j+0)*16, x2, eb1[2*j+0]));
        float r1 = eluf(dot16p(ew1 + (2*j+1)*16, x2, eb1[2*j+1]));
        h1p[j] = {r0, r1};
    }
    float z[16];
#pragma unroll
    for (int o = 0; o < 16; ++o) {
        float a = dot16p(ew2 + o*16, h1p, eb2[o]);
        z[o] = valid ? a : 0.0f;
    }

    if (valid) {
        float4* zp = reinterpret_cast<float4*>(zout + (size_t)i * 16);
        zp[0] = make_float4(z[0],  z[1],  z[2],  z[3]);
        zp[1] = make_float4(z[4],  z[5],  z[6],  z[7]);
        zp[2] = make_float4(z[8],  z[9],  z[10], z[11]);
        zp[3] = make_float4(z[12], z[13], z[14], z[15]);
    }

    int lane = tid & 63, wave = tid >> 6;
#pragma unroll
    for (int c = 0; c < 16; ++c) {
        float s = z[c];
        float q = z[c] * z[c];
#pragma unroll
        for (int m = 1; m < 64; m <<= 1) { s += __shfl_xor(s, m); q += __shfl_xor(q, m); }
        if (lane == 0) { wsum[wave][c] = s; wsum[wave][16 + c] = q; }
    }
    __syncthreads();
    if (tid < 32) {
        float t = wsum[0][tid] + wsum[1][tid] + wsum[2][tid] + wsum[3][tid];
        partials[(size_t)blockIdx.x * 32 + tid] = t;
    }
}

// ---------------- kB: reduce partials -> BN affine ----------------
__global__ __launch_bounds__(256) void kB(const float* __restrict__ partials, int nblk, int B,
                                          const float* __restrict__ bng, const float* __restrict__ bnb,
                                          float* __restrict__ bnp)
{
    int tid = threadIdx.x;
    int q = tid >> 3, k = tid & 7;
    int chunk = (nblk + 7) / 8;
    int j0 = k * chunk;
    int j1 = j0 + chunk; if (j1 > nblk) j1 = nblk;
    double s = 0.0;
    for (int j = j0; j < j1; ++j) s += (double)partials[(size_t)j * 32 + q];
    s += __shfl_xor(s, 4);
    s += __shfl_xor(s, 2);
    s += __shfl_xor(s, 1);
    __shared__ double tot[32];
    if (k == 0) tot[q] = s;
    __syncthreads();
    if (tid < 16) {
        double mu  = tot[tid] / (double)B;
        double var = tot[16 + tid] / (double)B - mu * mu;
        double a = (double)bng[tid] / sqrt(var + 1e-5);
        double b = (double)bnb[tid] - mu * a;
        bnp[tid]      = (float)a;
        bnp[16 + tid] = (float)b;
    }
}

// ---------------- k23: BN+FIR+noise + p-convs + pl + equalizer (packed fp32) ----------------
__global__ __launch_bounds__(256) void k23(float* __restrict__ crt,
    const float* __restrict__ fading, const float* __restrict__ noise,
    const float* __restrict__ bnp,
    const float* __restrict__ pc1w, const float* __restrict__ pc1b,
    const float* __restrict__ pc2s, const float* __restrict__ pc2b,
    const float* __restrict__ pc3w, const float* __restrict__ pc3b,
    const float* __restrict__ pc4w, const float* __restrict__ pc4b,
    const float* __restrict__ pc5s, const float* __restrict__ pc5b,
    const float* __restrict__ plw,  const float* __restrict__ plb,
    int B)
{
    int i = blockIdx.x * 256 + threadIdx.x;
    if (i >= B) return;

    // ---- head: BN affine + FIR + noise (scalar, cheap) ----
    {
        float zn[16];
        const float4* zp = reinterpret_cast<const float4*>(crt + (size_t)i * 16);
#pragma unroll
        for (int q = 0; q < 4; ++q) {
            float4 v = zp[q];
            zn[4*q+0] = fmaf(v.x, bnp[4*q+0], bnp[16 + 4*q+0]);
            zn[4*q+1] = fmaf(v.y, bnp[4*q+1], bnp[16 + 4*q+1]);
            zn[4*q+2] = fmaf(v.z, bnp[4*q+2], bnp[16 + 4*q+2]);
            zn[4*q+3] = fmaf(v.w, bnp[4*q+3], bnp[16 + 4*q+3]);
        }
        float f[6];
        const float2* fp = reinterpret_cast<const float2*>(fading + (size_t)i * 6);
#pragma unroll
        for (int q = 0; q < 3; ++q) { float2 v = fp[q]; f[2*q] = v.x; f[2*q+1] = v.y; }
        float cr[16];
#pragma unroll
        for (int n = 0; n < 8; ++n) {
            float re = f[0]*zn[2*n]   - f[1]*zn[2*n+1];
            float im = f[0]*zn[2*n+1] + f[1]*zn[2*n];
            if (n >= 1) { re += f[2]*zn[2*n-2] - f[3]*zn[2*n-1];
                          im += f[2]*zn[2*n-1] + f[3]*zn[2*n-2]; }
            if (n >= 2) { re += f[4]*zn[2*n-4] - f[5]*zn[2*n-3];
                          im += f[4]*zn[2*n-3] + f[5]*zn[2*n-4]; }
            cr[2*n] = re; cr[2*n+1] = im;
        }
        const float4* np_ = reinterpret_cast<const float4*>(noise + (size_t)i * 16);
#pragma unroll
        for (int q = 0; q < 4; ++q) {
            float4 v = np_[q];
            cr[4*q+0] = fmaf(v.x, NSCALE, cr[4*q+0]);
            cr[4*q+1] = fmaf(v.y, NSCALE, cr[4*q+1]);
            cr[4*q+2] = fmaf(v.z, NSCALE, cr[4*q+2]);
            cr[4*q+3] = fmaf(v.w, NSCALE, cr[4*q+3]);
        }
        float4* op = reinterpret_cast<float4*>(crt + (size_t)i * 16);
        op[0] = make_float4(cr[0],  cr[1],  cr[2],  cr[3]);
        op[1] = make_float4(cr[4],  cr[5],  cr[6],  cr[7]);
        op[2] = make_float4(cr[8],  cr[9],  cr[10], cr[11]);
        op[3] = make_float4(cr[12], cr[13], cr[14], cr[15]);
    }

    // ---- p-convs, packed. p5 accumulates as v2f across g (hadd deferred) ----
    v2f p5acc[16];
#pragma unroll
    for (int o = 0; o < 16; ++o) p5acc[o] = {pc5b[o], 0.0f};

#pragma unroll 1
    for (int g = 0; g < 3; ++g) {
        float crg[8];
        {
            const float4* cp = reinterpret_cast<const float4*>(crt + (size_t)i * 16 + 4 * g);
            float4 v0 = cp[0], v1 = cp[1];
            crg[0]=v0.x; crg[1]=v0.y; crg[2]=v0.z; crg[3]=v0.w;
            crg[4]=v1.x; crg[5]=v1.y; crg[6]=v1.z; crg[7]=v1.w;
        }
        // p1: 3 columns, scalar 4-dots, outputs packed as channel pairs
        v2f p1p[3][8];
#pragma unroll
        for (int c2 = 0; c2 < 3; ++c2) {
#pragma unroll
            for (int j = 0; j < 8; ++j) {
                float4 w0 = *reinterpret_cast<const float4*>(pc1w + (2*j+0)*4);
                float4 w1 = *reinterpret_cast<const float4*>(pc1w + (2*j+1)*4);
                float a0 = pc1b[2*j+0], a1 = pc1b[2*j+1];
                a0 = fmaf(w0.x, crg[c2+0], a0); a0 = fmaf(w0.y, crg[c2+1], a0);
                a0 = fmaf(w0.z, crg[c2+2], a0); a0 = fmaf(w0.w, crg[c2+3], a0);
                a1 = fmaf(w1.x, crg[c2+0], a1); a1 = fmaf(w1.y, crg[c2+1], a1);
                a1 = fmaf(w1.z, crg[c2+2], a1); a1 = fmaf(w1.w, crg[c2+3], a1);
                p1p[c2][j] = {reluf(a0), reluf(a1)};
            }
        }
        // p2: both output columns per o; weight rows loaded once, used twice
        v2f p2pair[16];   // {col0[o], col1[o]}
#pragma unroll
        for (int o = 0; o < 16; ++o) {
            const v2f* w0 = reinterpret_cast<const v2f*>(pc2s + o*16);        // tap0
            const v2f* w1 = reinterpret_cast<const v2f*>(pc2s + 256 + o*16);  // tap1
            v2f a0 = {pc2b[o], 0.0f}, a1 = {pc2b[o], 0.0f};
#pragma unroll
            for (int q = 0; q < 8; ++q) {
                v2f v0 = w0[q], v1 = w1[q];
                a0 = fma2(v0, p1p[0][q], a0);
                a0 = fma2(v1, p1p[1][q], a0);
                a1 = fma2(v0, p1p[1][q], a1);
                a1 = fma2(v1, p1p[2][q], a1);
            }
            p2pair[o] = {reluf(a0.x + a0.y), reluf(a1.x + a1.y)};
        }
        // p3: natural [o][ci][tap] rows of 32 = 16 v2f over p2pair
        v2f p3p[8];
#pragma unroll
        for (int j = 0; j < 8; ++j) {
            float r0 = reluf(dot32p(pc3w + (2*j+0)*32, p2pair, pc3b[2*j+0]));
            float r1 = reluf(dot32p(pc3w + (2*j+1)*32, p2pair, pc3b[2*j+1]));
            p3p[j] = {r0, r1};
        }
        // p4
        v2f p4p[8];
#pragma unroll
        for (int j = 0; j < 8; ++j) {
            float r0 = reluf(dot16p(pc4w + (2*j+0)*16, p3p, pc4b[2*j+0]));
            float r1 = reluf(dot16p(pc4w + (2*j+1)*16, p3p, pc4b[2*j+1]));
            p4p[j] = {r0, r1};
        }
        // p5 accumulate (v2f acc, no hadd)
#pragma unroll
        for (int o = 0; o < 16; ++o) {
            const v2f* w = reinterpret_cast<const v2f*>(pc5s + g*256 + o*16);
            v2f a = p5acc[o];
#pragma unroll
            for (int q = 0; q < 8; ++q) a = fma2(w[q], p4p[q], a);
            p5acc[o] = a;
        }
    }

    // pl
    v2f p5p[8];
#pragma unroll
    for (int j = 0; j < 8; ++j) {
        float r0 = reluf(p5acc[2*j+0].x + p5acc[2*j+0].y);
        float r1 = reluf(p5acc[2*j+1].x + p5acc[2*j+1].y);
        p5p[j] = {r0, r1};
    }
    float hh[16];
#pragma unroll
    for (int o = 0; o < 16; ++o) hh[o] = dot16p(plw + o*16, p5p, plb[o]);

    // equalizer (reload cr)
    float cr[16];
    {
        const float4* cp = reinterpret_cast<const float4*>(crt + (size_t)i * 16);
#pragma unroll
        for (int q = 0; q < 4; ++q) {
            float4 v = cp[q];
            cr[4*q+0] = v.x; cr[4*q+1] = v.y; cr[4*q+2] = v.z; cr[4*q+3] = v.w;
        }
    }
    float tr[16];
#pragma unroll
    for (int n = 0; n < 8; ++n) {
        float a = cr[2*n], b = cr[2*n+1];
        float c = hh[2*n], d = hh[2*n+1];
        float inv = 1.0f / (c*c + d*d);
        tr[2*n]   = (a*c + b*d) * inv;
        tr[2*n+1] = (b*c - a*d) * inv;
    }
    float4* op = reinterpret_cast<float4*>(crt + (size_t)i * 16);
    op[0] = make_float4(tr[0],  tr[1],  tr[2],  tr[3]);
    op[1] = make_float4(tr[4],  tr[5],  tr[6],  tr[7]);
    op[2] = make_float4(tr[8],  tr[9],  tr[10], tr[11]);
    op[3] = make_float4(tr[12], tr[13], tr[14], tr[15]);
}

// ---------------- k4: d-convs + dl1/dl2/dl3 (packed fp32) ----------------
__global__ __launch_bounds__(256) void k4(const float* __restrict__ trt,
    const float* __restrict__ dc1w, const float* __restrict__ dc1b,
    const float* __restrict__ dc2w, const float* __restrict__ dc2b,
    const float* __restrict__ dc3w, const float* __restrict__ dc3b,
    const float* __restrict__ dc4w, const float* __restrict__ dc4b,
    const float* __restrict__ dl1s, const float* __restrict__ dl1b,
    const float* __restrict__ dl2w, const float* __restrict__ dl2b,
    const float* __restrict__ dl3w, const float* __restrict__ dl3b,
    float* __restrict__ out, int B)
{
    int i = blockIdx.x * 256 + threadIdx.x;
    if (i >= B) return;

    v2f y2[16];
#pragma unroll
    for (int o = 0; o < 16; ++o) y2[o] = {dl1b[o], 0.0f};

#pragma unroll 1
    for (int t = 0; t < 8; ++t) {
        float2 tv = *reinterpret_cast<const float2*>(trt + (size_t)i * 16 + 2 * t);
        // d1: packed as {d1a[c], d1b[c]} per input channel c — matches dc2w [c][ci][ab]
        v2f d1p[8];
#pragma unroll
        for (int c = 0; c < 8; ++c) {
            float w = dc1w[c], b = dc1b[c];
            d1p[c] = {reluf(fmaf(w, tv.x, b)), reluf(fmaf(w, tv.y, b))};
        }
        v2f d2p[4];
#pragma unroll
        for (int j = 0; j < 4; ++j) {
            float r0 = reluf(dot16p(dc2w + (2*j+0)*16, d1p, dc2b[2*j+0]));
            float r1 = reluf(dot16p(dc2w + (2*j+1)*16, d1p, dc2b[2*j+1]));
            d2p[j] = {r0, r1};
        }
        v2f d3p[4];
#pragma unroll
        for (int j = 0; j < 4; ++j) {
            float r0 = reluf(dot8p(dc3w + (2*j+0)*8, d2p, dc3b[2*j+0]));
            float r1 = reluf(dot8p(dc3w + (2*j+1)*8, d2p, dc3b[2*j+1]));
            d3p[j] = {r0, r1};
        }
        v2f d4p[4];
#pragma unroll
        for (int j = 0; j < 4; ++j) {
            float r0 = reluf(dot8p(dc4w + (2*j+0)*8, d3p, dc4b[2*j+0]));
            float r1 = reluf(dot8p(dc4w + (2*j+1)*8, d3p, dc4b[2*j+1]));
            d4p[j] = {r0, r1};
        }
#pragma unroll
        for (int o = 0; o < 16; ++o) {
            const v2f* w = reinterpret_cast<const v2f*>(dl1s + t*128 + o*8);
            v2f a = y2[o];
#pragma unroll
            for (int q = 0; q < 4; ++q) a = fma2(w[q], d4p[q], a);
            y2[o] = a;
        }
    }

    v2f yp[8];
#pragma unroll
    for (int j = 0; j < 8; ++j) {
        float r0 = reluf(y2[2*j+0].x + y2[2*j+0].y);
        float r1 = reluf(y2[2*j+1].x + y2[2*j+1].y);
        yp[j] = {r0, r1};
    }
    v2f h2p[8];
#pragma unroll
    for (int j = 0; j < 8; ++j) {
        float r0 = eluf(dot16p(dl2w + (2*j+0)*16, yp, dl2b[2*j+0]));
        float r1 = eluf(dot16p(dl2w + (2*j+1)*16, yp, dl2b[2*j+1]));
        h2p[j] = {r0, r1};
    }
    float o16[16];
#pragma unroll
    for (int o = 0; o < 16; ++o) o16[o] = dot16p(dl3w + o*16, h2p, dl3b[o]);

    float4* op = reinterpret_cast<float4*>(out + (size_t)i * 16);
    op[0] = make_float4(o16[0],  o16[1],  o16[2],  o16[3]);
    op[1] = make_float4(o16[4],  o16[5],  o16[6],  o16[7]);
    op[2] = make_float4(o16[8],  o16[9],  o16[10], o16[11]);
    op[3] = make_float4(o16[12], o16[13], o16[14], o16[15]);
}

extern "C" void kernel_launch(void* const* d_in, const int* in_sizes, int n_in,
                              void* d_out, int out_size, void* d_ws, size_t ws_size,
                              hipStream_t stream)
{
    const float* x      = (const float*)d_in[0];
    const float* noise  = (const float*)d_in[1];
    const float* fading = (const float*)d_in[2];
    const float* ew1  = (const float*)d_in[3];
    const float* eb1  = (const float*)d_in[4];
    const float* ew2  = (const float*)d_in[5];
    const float* eb2  = (const float*)d_in[6];
    const float* bng  = (const float*)d_in[7];
    const float* bnb  = (const float*)d_in[8];
    const float* pc1w = (const float*)d_in[9];
    const float* pc1b = (const float*)d_in[10];
    const float* pc2w = (const float*)d_in[11];
    const float* pc2b = (const float*)d_in[12];
    const float* pc3w = (const float*)d_in[13];
    const float* pc3b = (const float*)d_in[14];
    const float* pc4w = (const float*)d_in[15];
    const float* pc4b = (const float*)d_in[16];
    const float* pc5w = (const float*)d_in[17];
    const float* pc5b = (const float*)d_in[18];
    const float* plw  = (const float*)d_in[19];
    const float* plb  = (const float*)d_in[20];
    const float* dc1w = (const float*)d_in[21];
    const float* dc1b = (const float*)d_in[22];
    const float* dc2w = (const float*)d_in[23];
    const float* dc2b = (const float*)d_in[24];
    const float* dc3w = (const float*)d_in[25];
    const float* dc3b = (const float*)d_in[26];
    const float* dc4w = (const float*)d_in[27];
    const float* dc4b = (const float*)d_in[28];
    const float* dl1w = (const float*)d_in[29];
    const float* dl1b = (const float*)d_in[30];
    const float* dl2w = (const float*)d_in[31];
    const float* dl2b = (const float*)d_in[32];
    const float* dl3w = (const float*)d_in[33];
    const float* dl3b = (const float*)d_in[34];

    int B = in_sizes[0] / 16;
    int nblk = (B + 255) / 256;

    float* partials = (float*)d_ws;                    // nblk*32
    float* bnp  = partials + (size_t)nblk * 32;        // 32
    float* pc2s = bnp + 32;                            // 512
    float* pc5s = pc2s + 512;                          // 768
    float* dl1s = pc5s + 768;                          // 1024
    float* crt  = dl1s + 1024;                         // B*16 (z -> cr -> tr in-place)

    kW<<<1, 256, 0, stream>>>(pc2w, pc5w, dl1w, pc2s, pc5s, dl1s);
    kA<<<nblk, 256, 0, stream>>>(x, ew1, eb1, ew2, eb2, partials, crt, B);
    kB<<<1, 256, 0, stream>>>(partials, nblk, B, bng, bnb, bnp);
    k23<<<nblk, 256, 0, stream>>>(crt, fading, noise, bnp,
                                  pc1w, pc1b, pc2s, pc2b, pc3w, pc3b, pc4w, pc4b, pc5s, pc5b,
                                  plw, plb, B);
    k4<<<nblk, 256, 0, stream>>>(crt,
                                 dc1w, dc1b, dc2w, dc2b, dc3w, dc3b, dc4w, dc4b,
                                 dl1s, dl1b, dl2w, dl2b, dl3w, dl3b,
                                 (float*)d_out, B);
}

// Round 11
// 226.210 us; speedup vs baseline: 10.4090x; 1.0072x over previous
//
#include <hip/hip_runtime.h>
#include <math.h>

#define NSCALE 0.44668359215096315f

typedef float v2f __attribute__((ext_vector_type(2)));

__device__ __forceinline__ v2f fma2(v2f a, v2f b, v2f c) { return __builtin_elementwise_fma(a, b, c); }
__device__ __forceinline__ v2f s2(float w) { v2f r = {w, w}; return r; }
__device__ __forceinline__ v2f max0(v2f v) { v2f z = {0.0f, 0.0f}; return __builtin_elementwise_max(v, z); }
__device__ __forceinline__ float eluf(float v)  { return v > 0.0f ? v : __expf(v) - 1.0f; }
__device__ __forceinline__ float reluf(float v) { return fmaxf(v, 0.0f); }

// packed dot helpers: weights contiguous, inputs pre-paired, acc float2 + horizontal add
__device__ __forceinline__ float dot16p(const float* __restrict__ w, const v2f p[8], float b) {
    const v2f* w2 = reinterpret_cast<const v2f*>(w);
    v2f a = {b, 0.0f};
#pragma unroll
    for (int q = 0; q < 8; ++q) a = fma2(w2[q], p[q], a);
    return a.x + a.y;
}
__device__ __forceinline__ float dot32p(const float* __restrict__ w, const v2f p[16], float b) {
    const v2f* w2 = reinterpret_cast<const v2f*>(w);
    v2f a = {b, 0.0f};
#pragma unroll
    for (int q = 0; q < 16; ++q) a = fma2(w2[q], p[q], a);
    return a.x + a.y;
}
__device__ __forceinline__ float dot8p(const float* __restrict__ w, const v2f p[4], float b) {
    const v2f* w2 = reinterpret_cast<const v2f*>(w);
    v2f a = {b, 0.0f};
#pragma unroll
    for (int q = 0; q < 4; ++q) a = fma2(w2[q], p[q], a);
    return a.x + a.y;
}

// ---------------- kAW: encoder -> z + partial sums; LAST block swizzles weights ----------------
__global__ __launch_bounds__(256) void kAW(const float* __restrict__ x,
                                           const float* __restrict__ ew1, const float* __restrict__ eb1,
                                           const float* __restrict__ ew2, const float* __restrict__ eb2,
                                           float* __restrict__ partials, float* __restrict__ zout, int B,
                                           const float* __restrict__ pc1w, const float* __restrict__ pc2w,
                                           const float* __restrict__ pc5w, const float* __restrict__ dl1w,
                                           float* __restrict__ pc1i, float* __restrict__ pc2s,
                                           float* __restrict__ pc5s, float* __restrict__ dl1s)
{
    int tid = threadIdx.x;
    if (blockIdx.x == gridDim.x - 1) {
        // weight swizzles (consumption-order layouts)
        for (int n = tid; n < 64; n += 256) {             // pc1w[o][k] -> pc1i[j][k][{2j,2j+1}]
            int j = n >> 3, k = (n >> 1) & 3, h = n & 1;
            pc1i[n] = pc1w[(2*j + h)*4 + k];
        }
        for (int j = tid; j < 512; j += 256) {            // pc2w[o*32+ci*2+tap] -> [tap][o][ci]
            int o = j >> 5, r = j & 31, ci = r >> 1, tap = r & 1;
            pc2s[tap*256 + o*16 + ci] = pc2w[j];
        }
        for (int j = tid; j < 768; j += 256) {            // pc5w[o*48+ci*3+g] -> [g][o][ci]
            int o = j / 48, r = j - o*48, ci = r / 3, g = r - ci*3;
            pc5s[g*256 + o*16 + ci] = pc5w[j];
        }
        for (int j = tid; j < 1024; j += 256) {           // dl1w[o*64+c*8+t] -> [t][o][c]
            int o = j >> 6, r = j & 63, c = r >> 3, t = r & 7;
            dl1s[t*128 + o*8 + c] = dl1w[j];
        }
        return;
    }

    __shared__ float wsum[4][32];
    int i = blockIdx.x * 256 + tid;
    bool valid = i < B;
    v2f x2[8];
    if (valid) {
        const float4* xp = reinterpret_cast<const float4*>(x + (size_t)i * 16);
#pragma unroll
        for (int q = 0; q < 4; ++q) {
            float4 v = xp[q];
            x2[2*q+0] = {v.x, v.y};
            x2[2*q+1] = {v.z, v.w};
        }
    } else {
#pragma unroll
        for (int q = 0; q < 8; ++q) x2[q] = {0.0f, 0.0f};
    }

    v2f h1p[8];
#pragma unroll
    for (int j = 0; j < 8; ++j) {
        float r0 = eluf(dot16p(ew1 + (2*j+0)*16, x2, eb1[2*j+0]));
        float r1 = eluf(dot16p(ew1 + (2*j+1)*16, x2, eb1[2*j+1]));
        h1p[j] = {r0, r1};
    }
    float z[16];
#pragma unroll
    for (int o = 0; o < 16; ++o) {
        float a = dot16p(ew2 + o*16, h1p, eb2[o]);
        z[o] = valid ? a : 0.0f;
    }

    if (valid) {
        float4* zp = reinterpret_cast<float4*>(zout + (size_t)i * 16);
        zp[0] = make_float4(z[0],  z[1],  z[2],  z[3]);
        zp[1] = make_float4(z[4],  z[5],  z[6],  z[7]);
        zp[2] = make_float4(z[8],  z[9],  z[10], z[11]);
        zp[3] = make_float4(z[12], z[13], z[14], z[15]);
    }

    int lane = tid & 63, wave = tid >> 6;
#pragma unroll
    for (int c = 0; c < 16; ++c) {
        float s = z[c];
        float q = z[c] * z[c];
#pragma unroll
        for (int m = 1; m < 64; m <<= 1) { s += __shfl_xor(s, m); q += __shfl_xor(q, m); }
        if (lane == 0) { wsum[wave][c] = s; wsum[wave][16 + c] = q; }
    }
    __syncthreads();
    if (tid < 32) {
        float t = wsum[0][tid] + wsum[1][tid] + wsum[2][tid] + wsum[3][tid];
        partials[(size_t)blockIdx.x * 32 + tid] = t;
    }
}

// ---------------- kB: reduce partials -> BN affine ----------------
__global__ __launch_bounds__(256) void kB(const float* __restrict__ partials, int nblk, int B,
                                          const float* __restrict__ bng, const float* __restrict__ bnb,
                                          float* __restrict__ bnp)
{
    int tid = threadIdx.x;
    int q = tid >> 3, k = tid & 7;
    int chunk = (nblk + 7) / 8;
    int j0 = k * chunk;
    int j1 = j0 + chunk; if (j1 > nblk) j1 = nblk;
    double s = 0.0;
    for (int j = j0; j < j1; ++j) s += (double)partials[(size_t)j * 32 + q];
    s += __shfl_xor(s, 4);
    s += __shfl_xor(s, 2);
    s += __shfl_xor(s, 1);
    __shared__ double tot[32];
    if (k == 0) tot[q] = s;
    __syncthreads();
    if (tid < 16) {
        double mu  = tot[tid] / (double)B;
        double var = tot[16 + tid] / (double)B - mu * mu;
        double a = (double)bng[tid] / sqrt(var + 1e-5);
        double b = (double)bnb[tid] - mu * a;
        bnp[tid]      = (float)a;
        bnp[16 + tid] = (float)b;
    }
}

// ---------------- kF: fused BN+FIR+noise + p-convs + pl + eq + d-convs + dl (packed fp32) ----------------
__global__ __launch_bounds__(256) void kF(float* __restrict__ crt,
    const float* __restrict__ fading, const float* __restrict__ noise,
    const float* __restrict__ bnp,
    const float* __restrict__ pc1i, const float* __restrict__ pc1b,
    const float* __restrict__ pc2s, const float* __restrict__ pc2b,
    const float* __restrict__ pc3w, const float* __restrict__ pc3b,
    const float* __restrict__ pc4w, const float* __restrict__ pc4b,
    const float* __restrict__ pc5s, const float* __restrict__ pc5b,
    const float* __restrict__ plw,  const float* __restrict__ plb,
    const float* __restrict__ dc1w, const float* __restrict__ dc1b,
    const float* __restrict__ dc2w, const float* __restrict__ dc2b,
    const float* __restrict__ dc3w, const float* __restrict__ dc3b,
    const float* __restrict__ dc4w, const float* __restrict__ dc4b,
    const float* __restrict__ dl1s, const float* __restrict__ dl1b,
    const float* __restrict__ dl2w, const float* __restrict__ dl2b,
    const float* __restrict__ dl3w, const float* __restrict__ dl3b,
    float* __restrict__ out, int B)
{
    int i = blockIdx.x * 256 + threadIdx.x;
    if (i >= B) return;

    // ---- head: BN affine + FIR + noise ----
    {
        float zn[16];
        const float4* zp = reinterpret_cast<const float4*>(crt + (size_t)i * 16);
#pragma unroll
        for (int q = 0; q < 4; ++q) {
            float4 v = zp[q];
            zn[4*q+0] = fmaf(v.x, bnp[4*q+0], bnp[16 + 4*q+0]);
            zn[4*q+1] = fmaf(v.y, bnp[4*q+1], bnp[16 + 4*q+1]);
            zn[4*q+2] = fmaf(v.z, bnp[4*q+2], bnp[16 + 4*q+2]);
            zn[4*q+3] = fmaf(v.w, bnp[4*q+3], bnp[16 + 4*q+3]);
        }
        float f[6];
        const float2* fp = reinterpret_cast<const float2*>(fading + (size_t)i * 6);
#pragma unroll
        for (int q = 0; q < 3; ++q) { float2 v = fp[q]; f[2*q] = v.x; f[2*q+1] = v.y; }
        float cr[16];
#pragma unroll
        for (int n = 0; n < 8; ++n) {
            float re = f[0]*zn[2*n]   - f[1]*zn[2*n+1];
            float im = f[0]*zn[2*n+1] + f[1]*zn[2*n];
            if (n >= 1) { re += f[2]*zn[2*n-2] - f[3]*zn[2*n-1];
                          im += f[2]*zn[2*n-1] + f[3]*zn[2*n-2]; }
            if (n >= 2) { re += f[4]*zn[2*n-4] - f[5]*zn[2*n-3];
                          im += f[4]*zn[2*n-3] + f[5]*zn[2*n-4]; }
            cr[2*n] = re; cr[2*n+1] = im;
        }
        const float4* np_ = reinterpret_cast<const float4*>(noise + (size_t)i * 16);
#pragma unroll
        for (int q = 0; q < 4; ++q) {
            float4 v = np_[q];
            cr[4*q+0] = fmaf(v.x, NSCALE, cr[4*q+0]);
            cr[4*q+1] = fmaf(v.y, NSCALE, cr[4*q+1]);
            cr[4*q+2] = fmaf(v.z, NSCALE, cr[4*q+2]);
            cr[4*q+3] = fmaf(v.w, NSCALE, cr[4*q+3]);
        }
        float4* op = reinterpret_cast<float4*>(crt + (size_t)i * 16);
        op[0] = make_float4(cr[0],  cr[1],  cr[2],  cr[3]);
        op[1] = make_float4(cr[4],  cr[5],  cr[6],  cr[7]);
        op[2] = make_float4(cr[8],  cr[9],  cr[10], cr[11]);
        op[3] = make_float4(cr[12], cr[13], cr[14], cr[15]);
    }

    // ---- p-convs, packed; p5 accumulates as v2f across g ----
    v2f p5acc[16];
#pragma unroll
    for (int o = 0; o < 16; ++o) p5acc[o] = {pc5b[o], 0.0f};

#pragma unroll 1
    for (int g = 0; g < 3; ++g) {
        float crg[8];
        {
            const float4* cp = reinterpret_cast<const float4*>(crt + (size_t)i * 16 + 4 * g);
            float4 v0 = cp[0], v1 = cp[1];
            crg[0]=v0.x; crg[1]=v0.y; crg[2]=v0.z; crg[3]=v0.w;
            crg[4]=v1.x; crg[5]=v1.y; crg[6]=v1.z; crg[7]=v1.w;
        }
        // p1: packed row-pairs via interleaved pc1i; output directly in pair layout
        v2f p1p[3][8];
#pragma unroll
        for (int c2 = 0; c2 < 3; ++c2) {
#pragma unroll
            for (int j = 0; j < 8; ++j) {
                const v2f* wi = reinterpret_cast<const v2f*>(pc1i + j*8);
                v2f a = *reinterpret_cast<const v2f*>(pc1b + 2*j);
                a = fma2(wi[0], s2(crg[c2+0]), a);
                a = fma2(wi[1], s2(crg[c2+1]), a);
                a = fma2(wi[2], s2(crg[c2+2]), a);
                a = fma2(wi[3], s2(crg[c2+3]), a);
                p1p[c2][j] = max0(a);
            }
        }
        // p2: both output columns per o; weight rows loaded once, used twice
        v2f p2pair[16];   // {col0[o], col1[o]}
#pragma unroll
        for (int o = 0; o < 16; ++o) {
            const v2f* w0 = reinterpret_cast<const v2f*>(pc2s + o*16);        // tap0
            const v2f* w1 = reinterpret_cast<const v2f*>(pc2s + 256 + o*16);  // tap1
            v2f a0 = {pc2b[o], 0.0f}, a1 = {pc2b[o], 0.0f};
#pragma unroll
            for (int q = 0; q < 8; ++q) {
                v2f v0 = w0[q], v1 = w1[q];
                a0 = fma2(v0, p1p[0][q], a0);
                a0 = fma2(v1, p1p[1][q], a0);
                a1 = fma2(v0, p1p[1][q], a1);
                a1 = fma2(v1, p1p[2][q], a1);
            }
            p2pair[o] = {reluf(a0.x + a0.y), reluf(a1.x + a1.y)};
        }
        // p3
        v2f p3p[8];
#pragma unroll
        for (int j = 0; j < 8; ++j) {
            float r0 = reluf(dot32p(pc3w + (2*j+0)*32, p2pair, pc3b[2*j+0]));
            float r1 = reluf(dot32p(pc3w + (2*j+1)*32, p2pair, pc3b[2*j+1]));
            p3p[j] = {r0, r1};
        }
        // p4
        v2f p4p[8];
#pragma unroll
        for (int j = 0; j < 8; ++j) {
            float r0 = reluf(dot16p(pc4w + (2*j+0)*16, p3p, pc4b[2*j+0]));
            float r1 = reluf(dot16p(pc4w + (2*j+1)*16, p3p, pc4b[2*j+1]));
            p4p[j] = {r0, r1};
        }
        // p5 accumulate
#pragma unroll
        for (int o = 0; o < 16; ++o) {
            const v2f* w = reinterpret_cast<const v2f*>(pc5s + g*256 + o*16);
            v2f a = p5acc[o];
#pragma unroll
            for (int q = 0; q < 8; ++q) a = fma2(w[q], p4p[q], a);
            p5acc[o] = a;
        }
    }

    // pl
    v2f p5p[8];
#pragma unroll
    for (int j = 0; j < 8; ++j) {
        float r0 = reluf(p5acc[2*j+0].x + p5acc[2*j+0].y);
        float r1 = reluf(p5acc[2*j+1].x + p5acc[2*j+1].y);
        p5p[j] = {r0, r1};
    }
    float hh[16];
#pragma unroll
    for (int o = 0; o < 16; ++o) hh[o] = dot16p(plw + o*16, p5p, plb[o]);

    // equalizer (reload cr, write tr in place)
    {
        float cr[16];
        const float4* cp = reinterpret_cast<const float4*>(crt + (size_t)i * 16);
#pragma unroll
        for (int q = 0; q < 4; ++q) {
            float4 v = cp[q];
            cr[4*q+0] = v.x; cr[4*q+1] = v.y; cr[4*q+2] = v.z; cr[4*q+3] = v.w;
        }
        float tr[16];
#pragma unroll
        for (int n = 0; n < 8; ++n) {
            float a = cr[2*n], b = cr[2*n+1];
            float c = hh[2*n], d = hh[2*n+1];
            float inv = 1.0f / (c*c + d*d);
            tr[2*n]   = (a*c + b*d) * inv;
            tr[2*n+1] = (b*c - a*d) * inv;
        }
        float4* op = reinterpret_cast<float4*>(crt + (size_t)i * 16);
        op[0] = make_float4(tr[0],  tr[1],  tr[2],  tr[3]);
        op[1] = make_float4(tr[4],  tr[5],  tr[6],  tr[7]);
        op[2] = make_float4(tr[8],  tr[9],  tr[10], tr[11]);
        op[3] = make_float4(tr[12], tr[13], tr[14], tr[15]);
    }

    // ---- decoder phase: d-convs + dl1/dl2/dl3 (reads own tr from crt) ----
    v2f y2[16];
#pragma unroll
    for (int o = 0; o < 16; ++o) y2[o] = {dl1b[o], 0.0f};

#pragma unroll 1
    for (int t = 0; t < 8; ++t) {
        float2 tv = *reinterpret_cast<const float2*>(crt + (size_t)i * 16 + 2 * t);
        v2f tv2 = {tv.x, tv.y};
        // d1 packed: {d1a[c], d1b[c]} per input channel c
        v2f d1p[8];
#pragma unroll
        for (int c = 0; c < 8; ++c) {
            d1p[c] = max0(fma2(s2(dc1w[c]), tv2, s2(dc1b[c])));
        }
        v2f d2p[4];
#pragma unroll
        for (int j = 0; j < 4; ++j) {
            float r0 = reluf(dot16p(dc2w + (2*j+0)*16, d1p, dc2b[2*j+0]));
            float r1 = reluf(dot16p(dc2w + (2*j+1)*16, d1p, dc2b[2*j+1]));
            d2p[j] = {r0, r1};
        }
        v2f d3p[4];
#pragma unroll
        for (int j = 0; j < 4; ++j) {
            float r0 = reluf(dot8p(dc3w + (2*j+0)*8, d2p, dc3b[2*j+0]));
            float r1 = reluf(dot8p(dc3w + (2*j+1)*8, d2p, dc3b[2*j+1]));
            d3p[j] = {r0, r1};
        }
        v2f d4p[4];
#pragma unroll
        for (int j = 0; j < 4; ++j) {
            float r0 = reluf(dot8p(dc4w + (2*j+0)*8, d3p, dc4b[2*j+0]));
            float r1 = reluf(dot8p(dc4w + (2*j+1)*8, d3p, dc4b[2*j+1]));
            d4p[j] = {r0, r1};
        }
#pragma unroll
        for (int o = 0; o < 16; ++o) {
            const v2f* w = reinterpret_cast<const v2f*>(dl1s + t*128 + o*8);
            v2f a = y2[o];
#pragma unroll
            for (int q = 0; q < 4; ++q) a = fma2(w[q], d4p[q], a);
            y2[o] = a;
        }
    }

    v2f yp[8];
#pragma unroll
    for (int j = 0; j < 8; ++j) {
        float r0 = reluf(y2[2*j+0].x + y2[2*j+0].y);
        float r1 = reluf(y2[2*j+1].x + y2[2*j+1].y);
        yp[j] = {r0, r1};
    }
    v2f h2p[8];
#pragma unroll
    for (int j = 0; j < 8; ++j) {
        float r0 = eluf(dot16p(dl2w + (2*j+0)*16, yp, dl2b[2*j+0]));
        float r1 = eluf(dot16p(dl2w + (2*j+1)*16, yp, dl2b[2*j+1]));
        h2p[j] = {r0, r1};
    }
    float o16[16];
#pragma unroll
    for (int o = 0; o < 16; ++o) o16[o] = dot16p(dl3w + o*16, h2p, dl3b[o]);

    float4* op = reinterpret_cast<float4*>(out + (size_t)i * 16);
    op[0] = make_float4(o16[0],  o16[1],  o16[2],  o16[3]);
    op[1] = make_float4(o16[4],  o16[5],  o16[6],  o16[7]);
    op[2] = make_float4(o16[8],  o16[9],  o16[10], o16[11]);
    op[3] = make_float4(o16[12], o16[13], o16[14], o16[15]);
}

extern "C" void kernel_launch(void* const* d_in, const int* in_sizes, int n_in,
                              void* d_out, int out_size, void* d_ws, size_t ws_size,
                              hipStream_t stream)
{
    const float* x      = (const float*)d_in[0];
    const float* noise  = (const float*)d_in[1];
    const float* fading = (const float*)d_in[2];
    const float* ew1  = (const float*)d_in[3];
    const float* eb1  = (const float*)d_in[4];
    const float* ew2  = (const float*)d_in[5];
    const float* eb2  = (const float*)d_in[6];
    const float* bng  = (const float*)d_in[7];
    const float* bnb  = (const float*)d_in[8];
    const float* pc1w = (const float*)d_in[9];
    const float* pc1b = (const float*)d_in[10];
    const float* pc2w = (const float*)d_in[11];
    const float* pc2b = (const float*)d_in[12];
    const float* pc3w = (const float*)d_in[13];
    const float* pc3b = (const float*)d_in[14];
    const float* pc4w = (const float*)d_in[15];
    const float* pc4b = (const float*)d_in[16];
    const float* pc5w = (const float*)d_in[17];
    const float* pc5b = (const float*)d_in[18];
    const float* plw  = (const float*)d_in[19];
    const float* plb  = (const float*)d_in[20];
    const float* dc1w = (const float*)d_in[21];
    const float* dc1b = (const float*)d_in[22];
    const float* dc2w = (const float*)d_in[23];
    const float* dc2b = (const float*)d_in[24];
    const float* dc3w = (const float*)d_in[25];
    const float* dc3b = (const float*)d_in[26];
    const float* dc4w = (const float*)d_in[27];
    const float* dc4b = (const float*)d_in[28];
    const float* dl1w = (const float*)d_in[29];
    const float* dl1b = (const float*)d_in[30];
    const float* dl2w = (const float*)d_in[31];
    const float* dl2b = (const float*)d_in[32];
    const float* dl3w = (const float*)d_in[33];
    const float* dl3b = (const float*)d_in[34];

    int B = in_sizes[0] / 16;
    int nblk = (B + 255) / 256;

    float* partials = (float*)d_ws;                    // nblk*32
    float* bnp  = partials + (size_t)nblk * 32;        // 32
    float* pc2s = bnp + 32;                            // 512
    float* pc5s = pc2s + 512;                          // 768
    float* dl1s = pc5s + 768;                          // 1024
    float* pc1i = dl1s + 1024;                         // 128
    float* crt  = pc1i + 128;                          // B*16 (z -> cr -> tr in-place)

    kAW<<<nblk + 1, 256, 0, stream>>>(x, ew1, eb1, ew2, eb2, partials, crt, B,
                                      pc1w, pc2w, pc5w, dl1w,
                                      pc1i, pc2s, pc5s, dl1s);
    kB<<<1, 256, 0, stream>>>(partials, nblk, B, bng, bnb, bnp);
    kF<<<nblk, 256, 0, stream>>>(crt, fading, noise, bnp,
                                 pc1i, pc1b, pc2s, pc2b, pc3w, pc3b, pc4w, pc4b, pc5s, pc5b,
                                 plw, plb,
                                 dc1w, dc1b, dc2w, dc2b, dc3w, dc3b, dc4w, dc4b,
                                 dl1s, dl1b, dl2w, dl2b, dl3w, dl3b,
                                 (float*)d_out, B);
}

// Round 12
// 224.614 us; speedup vs baseline: 10.4830x; 1.0071x over previous
//
#include <hip/hip_runtime.h>
#include <math.h>

#define NSCALE 0.44668359215096315f

typedef float v2f __attribute__((ext_vector_type(2)));

__device__ __forceinline__ v2f fma2(v2f a, v2f b, v2f c) { return __builtin_elementwise_fma(a, b, c); }
__device__ __forceinline__ v2f s2(float w) { v2f r = {w, w}; return r; }
__device__ __forceinline__ v2f max0(v2f v) { v2f z = {0.0f, 0.0f}; return __builtin_elementwise_max(v, z); }
__device__ __forceinline__ float eluf(float v)  { return v > 0.0f ? v : __expf(v) - 1.0f; }
__device__ __forceinline__ float reluf(float v) { return fmaxf(v, 0.0f); }

// packed dot helpers: weights contiguous, inputs pre-paired, acc float2 + horizontal add
__device__ __forceinline__ float dot16p(const float* __restrict__ w, const v2f p[8], float b) {
    const v2f* w2 = reinterpret_cast<const v2f*>(w);
    v2f a = {b, 0.0f};
#pragma unroll
    for (int q = 0; q < 8; ++q) a = fma2(w2[q], p[q], a);
    return a.x + a.y;
}
__device__ __forceinline__ float dot32p(const float* __restrict__ w, const v2f p[16], float b) {
    const v2f* w2 = reinterpret_cast<const v2f*>(w);
    v2f a = {b, 0.0f};
#pragma unroll
    for (int q = 0; q < 16; ++q) a = fma2(w2[q], p[q], a);
    return a.x + a.y;
}
__device__ __forceinline__ float dot8p(const float* __restrict__ w, const v2f p[4], float b) {
    const v2f* w2 = reinterpret_cast<const v2f*>(w);
    v2f a = {b, 0.0f};
#pragma unroll
    for (int q = 0; q < 4; ++q) a = fma2(w2[q], p[q], a);
    return a.x + a.y;
}

// ---------------- kAW: encoder -> z + partial sums; LAST block swizzles weights ----------------
__global__ __launch_bounds__(256) void kAW(const float* __restrict__ x,
                                           const float* __restrict__ ew1, const float* __restrict__ eb1,
                                           const float* __restrict__ ew2, const float* __restrict__ eb2,
                                           float* __restrict__ partials, float* __restrict__ zout, int B,
                                           const float* __restrict__ pc1w, const float* __restrict__ pc2w,
                                           const float* __restrict__ pc5w, const float* __restrict__ dl1w,
                                           float* __restrict__ pc1i, float* __restrict__ pc2s,
                                           float* __restrict__ pc5s, float* __restrict__ dl1s)
{
    int tid = threadIdx.x;
    if (blockIdx.x == gridDim.x - 1) {
        for (int n = tid; n < 64; n += 256) {             // pc1w[o][k] -> pc1i[j][k][{2j,2j+1}]
            int j = n >> 3, k = (n >> 1) & 3, h = n & 1;
            pc1i[n] = pc1w[(2*j + h)*4 + k];
        }
        for (int j = tid; j < 512; j += 256) {            // pc2w[o*32+ci*2+tap] -> [tap][o][ci]
            int o = j >> 5, r = j & 31, ci = r >> 1, tap = r & 1;
            pc2s[tap*256 + o*16 + ci] = pc2w[j];
        }
        for (int j = tid; j < 768; j += 256) {            // pc5w[o*48+ci*3+g] -> [g][o][ci]
            int o = j / 48, r = j - o*48, ci = r / 3, g = r - ci*3;
            pc5s[g*256 + o*16 + ci] = pc5w[j];
        }
        for (int j = tid; j < 1024; j += 256) {           // dl1w[o*64+c*8+t] -> [t][o][c]
            int o = j >> 6, r = j & 63, c = r >> 3, t = r & 7;
            dl1s[t*128 + o*8 + c] = dl1w[j];
        }
        return;
    }

    __shared__ float wsum[4][32];
    int i = blockIdx.x * 256 + tid;
    bool valid = i < B;
    v2f x2[8];
    if (valid) {
        const float4* xp = reinterpret_cast<const float4*>(x + (size_t)i * 16);
#pragma unroll
        for (int q = 0; q < 4; ++q) {
            float4 v = xp[q];
            x2[2*q+0] = {v.x, v.y};
            x2[2*q+1] = {v.z, v.w};
        }
    } else {
#pragma unroll
        for (int q = 0; q < 8; ++q) x2[q] = {0.0f, 0.0f};
    }

    v2f h1p[8];
#pragma unroll
    for (int j = 0; j < 8; ++j) {
        float r0 = eluf(dot16p(ew1 + (2*j+0)*16, x2, eb1[2*j+0]));
        float r1 = eluf(dot16p(ew1 + (2*j+1)*16, x2, eb1[2*j+1]));
        h1p[j] = {r0, r1};
    }
    float z[16];
#pragma unroll
    for (int o = 0; o < 16; ++o) {
        float a = dot16p(ew2 + o*16, h1p, eb2[o]);
        z[o] = valid ? a : 0.0f;
    }

    if (valid) {
        float4* zp = reinterpret_cast<float4*>(zout + (size_t)i * 16);
        zp[0] = make_float4(z[0],  z[1],  z[2],  z[3]);
        zp[1] = make_float4(z[4],  z[5],  z[6],  z[7]);
        zp[2] = make_float4(z[8],  z[9],  z[10], z[11]);
        zp[3] = make_float4(z[12], z[13], z[14], z[15]);
    }

    int lane = tid & 63, wave = tid >> 6;
#pragma unroll
    for (int c = 0; c < 16; ++c) {
        float s = z[c];
        float q = z[c] * z[c];
#pragma unroll
        for (int m = 1; m < 64; m <<= 1) { s += __shfl_xor(s, m); q += __shfl_xor(q, m); }
        if (lane == 0) { wsum[wave][c] = s; wsum[wave][16 + c] = q; }
    }
    __syncthreads();
    if (tid < 32) {
        float t = wsum[0][tid] + wsum[1][tid] + wsum[2][tid] + wsum[3][tid];
        partials[(size_t)blockIdx.x * 32 + tid] = t;
    }
}

// ---------------- kB: reduce partials -> BN affine ----------------
__global__ __launch_bounds__(256) void kB(const float* __restrict__ partials, int nblk, int B,
                                          const float* __restrict__ bng, const float* __restrict__ bnb,
                                          float* __restrict__ bnp)
{
    int tid = threadIdx.x;
    int q = tid >> 3, k = tid & 7;
    int chunk = (nblk + 7) / 8;
    int j0 = k * chunk;
    int j1 = j0 + chunk; if (j1 > nblk) j1 = nblk;
    double s = 0.0;
    for (int j = j0; j < j1; ++j) s += (double)partials[(size_t)j * 32 + q];
    s += __shfl_xor(s, 4);
    s += __shfl_xor(s, 2);
    s += __shfl_xor(s, 1);
    __shared__ double tot[32];
    if (k == 0) tot[q] = s;
    __syncthreads();
    if (tid < 16) {
        double mu  = tot[tid] / (double)B;
        double var = tot[16 + tid] / (double)B - mu * mu;
        double a = (double)bng[tid] / sqrt(var + 1e-5);
        double b = (double)bnb[tid] - mu * a;
        bnp[tid]      = (float)a;
        bnp[16 + tid] = (float)b;
    }
}

// ---------------- kF: fused pipeline; decoder fully unrolled with tr in registers ----------------
__global__ __launch_bounds__(256) void kF(float* __restrict__ crt,
    const float* __restrict__ fading, const float* __restrict__ noise,
    const float* __restrict__ bnp,
    const float* __restrict__ pc1i, const float* __restrict__ pc1b,
    const float* __restrict__ pc2s, const float* __restrict__ pc2b,
    const float* __restrict__ pc3w, const float* __restrict__ pc3b,
    const float* __restrict__ pc4w, const float* __restrict__ pc4b,
    const float* __restrict__ pc5s, const float* __restrict__ pc5b,
    const float* __restrict__ plw,  const float* __restrict__ plb,
    const float* __restrict__ dc1w, const float* __restrict__ dc1b,
    const float* __restrict__ dc2w, const float* __restrict__ dc2b,
    const float* __restrict__ dc3w, const float* __restrict__ dc3b,
    const float* __restrict__ dc4w, const float* __restrict__ dc4b,
    const float* __restrict__ dl1s, const float* __restrict__ dl1b,
    const float* __restrict__ dl2w, const float* __restrict__ dl2b,
    const float* __restrict__ dl3w, const float* __restrict__ dl3b,
    float* __restrict__ out, int B)
{
    int i = blockIdx.x * 256 + threadIdx.x;
    if (i >= B) return;

    // ---- head: BN affine + FIR + noise; cr stays LIVE through the equalizer ----
    float cr[16];
    {
        float zn[16];
        const float4* zp = reinterpret_cast<const float4*>(crt + (size_t)i * 16);
#pragma unroll
        for (int q = 0; q < 4; ++q) {
            float4 v = zp[q];
            zn[4*q+0] = fmaf(v.x, bnp[4*q+0], bnp[16 + 4*q+0]);
            zn[4*q+1] = fmaf(v.y, bnp[4*q+1], bnp[16 + 4*q+1]);
            zn[4*q+2] = fmaf(v.z, bnp[4*q+2], bnp[16 + 4*q+2]);
            zn[4*q+3] = fmaf(v.w, bnp[4*q+3], bnp[16 + 4*q+3]);
        }
        float f[6];
        const float2* fp = reinterpret_cast<const float2*>(fading + (size_t)i * 6);
#pragma unroll
        for (int q = 0; q < 3; ++q) { float2 v = fp[q]; f[2*q] = v.x; f[2*q+1] = v.y; }
#pragma unroll
        for (int n = 0; n < 8; ++n) {
            float re = f[0]*zn[2*n]   - f[1]*zn[2*n+1];
            float im = f[0]*zn[2*n+1] + f[1]*zn[2*n];
            if (n >= 1) { re += f[2]*zn[2*n-2] - f[3]*zn[2*n-1];
                          im += f[2]*zn[2*n-1] + f[3]*zn[2*n-2]; }
            if (n >= 2) { re += f[4]*zn[2*n-4] - f[5]*zn[2*n-3];
                          im += f[4]*zn[2*n-3] + f[5]*zn[2*n-4]; }
            cr[2*n] = re; cr[2*n+1] = im;
        }
        const float4* np_ = reinterpret_cast<const float4*>(noise + (size_t)i * 16);
#pragma unroll
        for (int q = 0; q < 4; ++q) {
            float4 v = np_[q];
            cr[4*q+0] = fmaf(v.x, NSCALE, cr[4*q+0]);
            cr[4*q+1] = fmaf(v.y, NSCALE, cr[4*q+1]);
            cr[4*q+2] = fmaf(v.z, NSCALE, cr[4*q+2]);
            cr[4*q+3] = fmaf(v.w, NSCALE, cr[4*q+3]);
        }
        // store cr for the rolled g-loop's runtime-g slice reads (proven idiom)
        float4* op = reinterpret_cast<float4*>(crt + (size_t)i * 16);
        op[0] = make_float4(cr[0],  cr[1],  cr[2],  cr[3]);
        op[1] = make_float4(cr[4],  cr[5],  cr[6],  cr[7]);
        op[2] = make_float4(cr[8],  cr[9],  cr[10], cr[11]);
        op[3] = make_float4(cr[12], cr[13], cr[14], cr[15]);
    }

    // ---- p-convs, packed; p5 accumulates as v2f across g (rolled, proven no-spill) ----
    v2f p5acc[16];
#pragma unroll
    for (int o = 0; o < 16; ++o) p5acc[o] = {pc5b[o], 0.0f};

#pragma unroll 1
    for (int g = 0; g < 3; ++g) {
        float crg[8];
        {
            const float4* cp = reinterpret_cast<const float4*>(crt + (size_t)i * 16 + 4 * g);
            float4 v0 = cp[0], v1 = cp[1];
            crg[0]=v0.x; crg[1]=v0.y; crg[2]=v0.z; crg[3]=v0.w;
            crg[4]=v1.x; crg[5]=v1.y; crg[6]=v1.z; crg[7]=v1.w;
        }
        v2f p1p[3][8];
#pragma unroll
        for (int c2 = 0; c2 < 3; ++c2) {
#pragma unroll
            for (int j = 0; j < 8; ++j) {
                const v2f* wi = reinterpret_cast<const v2f*>(pc1i + j*8);
                v2f a = *reinterpret_cast<const v2f*>(pc1b + 2*j);
                a = fma2(wi[0], s2(crg[c2+0]), a);
                a = fma2(wi[1], s2(crg[c2+1]), a);
                a = fma2(wi[2], s2(crg[c2+2]), a);
                a = fma2(wi[3], s2(crg[c2+3]), a);
                p1p[c2][j] = max0(a);
            }
        }
        v2f p2pair[16];
#pragma unroll
        for (int o = 0; o < 16; ++o) {
            const v2f* w0 = reinterpret_cast<const v2f*>(pc2s + o*16);
            const v2f* w1 = reinterpret_cast<const v2f*>(pc2s + 256 + o*16);
            v2f a0 = {pc2b[o], 0.0f}, a1 = {pc2b[o], 0.0f};
#pragma unroll
            for (int q = 0; q < 8; ++q) {
                v2f v0 = w0[q], v1 = w1[q];
                a0 = fma2(v0, p1p[0][q], a0);
                a0 = fma2(v1, p1p[1][q], a0);
                a1 = fma2(v0, p1p[1][q], a1);
                a1 = fma2(v1, p1p[2][q], a1);
            }
            p2pair[o] = {reluf(a0.x + a0.y), reluf(a1.x + a1.y)};
        }
        v2f p3p[8];
#pragma unroll
        for (int j = 0; j < 8; ++j) {
            float r0 = reluf(dot32p(pc3w + (2*j+0)*32, p2pair, pc3b[2*j+0]));
            float r1 = reluf(dot32p(pc3w + (2*j+1)*32, p2pair, pc3b[2*j+1]));
            p3p[j] = {r0, r1};
        }
        v2f p4p[8];
#pragma unroll
        for (int j = 0; j < 8; ++j) {
            float r0 = reluf(dot16p(pc4w + (2*j+0)*16, p3p, pc4b[2*j+0]));
            float r1 = reluf(dot16p(pc4w + (2*j+1)*16, p3p, pc4b[2*j+1]));
            p4p[j] = {r0, r1};
        }
#pragma unroll
        for (int o = 0; o < 16; ++o) {
            const v2f* w = reinterpret_cast<const v2f*>(pc5s + g*256 + o*16);
            v2f a = p5acc[o];
#pragma unroll
            for (int q = 0; q < 8; ++q) a = fma2(w[q], p4p[q], a);
            p5acc[o] = a;
        }
    }

    // pl
    v2f p5p[8];
#pragma unroll
    for (int j = 0; j < 8; ++j) {
        float r0 = reluf(p5acc[2*j+0].x + p5acc[2*j+0].y);
        float r1 = reluf(p5acc[2*j+1].x + p5acc[2*j+1].y);
        p5p[j] = {r0, r1};
    }
    float hh[16];
#pragma unroll
    for (int o = 0; o < 16; ++o) hh[o] = dot16p(plw + o*16, p5p, plb[o]);

    // equalizer — cr still live, tr stays in registers (no crt round-trip)
    float tr[16];
#pragma unroll
    for (int n = 0; n < 8; ++n) {
        float a = cr[2*n], b = cr[2*n+1];
        float c = hh[2*n], d = hh[2*n+1];
        float inv = 1.0f / (c*c + d*d);
        tr[2*n]   = (a*c + b*d) * inv;
        tr[2*n+1] = (b*c - a*d) * inv;
    }

    // ---- decoder: FULLY UNROLLED t-loop, tr in registers (8 independent chains) ----
    v2f y2[16];
#pragma unroll
    for (int o = 0; o < 16; ++o) y2[o] = {dl1b[o], 0.0f};

#pragma unroll
    for (int t = 0; t < 8; ++t) {
        v2f tv2 = {tr[2*t], tr[2*t+1]};
        v2f d1p[8];
#pragma unroll
        for (int c = 0; c < 8; ++c) {
            d1p[c] = max0(fma2(s2(dc1w[c]), tv2, s2(dc1b[c])));
        }
        v2f d2p[4];
#pragma unroll
        for (int j = 0; j < 4; ++j) {
            float r0 = reluf(dot16p(dc2w + (2*j+0)*16, d1p, dc2b[2*j+0]));
            float r1 = reluf(dot16p(dc2w + (2*j+1)*16, d1p, dc2b[2*j+1]));
            d2p[j] = {r0, r1};
        }
        v2f d3p[4];
#pragma unroll
        for (int j = 0; j < 4; ++j) {
            float r0 = reluf(dot8p(dc3w + (2*j+0)*8, d2p, dc3b[2*j+0]));
            float r1 = reluf(dot8p(dc3w + (2*j+1)*8, d2p, dc3b[2*j+1]));
            d3p[j] = {r0, r1};
        }
        v2f d4p[4];
#pragma unroll
        for (int j = 0; j < 4; ++j) {
            float r0 = reluf(dot8p(dc4w + (2*j+0)*8, d3p, dc4b[2*j+0]));
            float r1 = reluf(dot8p(dc4w + (2*j+1)*8, d3p, dc4b[2*j+1]));
            d4p[j] = {r0, r1};
        }
#pragma unroll
        for (int o = 0; o < 16; ++o) {
            const v2f* w = reinterpret_cast<const v2f*>(dl1s + t*128 + o*8);
            v2f a = y2[o];
#pragma unroll
            for (int q = 0; q < 4; ++q) a = fma2(w[q], d4p[q], a);
            y2[o] = a;
        }
    }

    v2f yp[8];
#pragma unroll
    for (int j = 0; j < 8; ++j) {
        float r0 = reluf(y2[2*j+0].x + y2[2*j+0].y);
        float r1 = reluf(y2[2*j+1].x + y2[2*j+1].y);
        yp[j] = {r0, r1};
    }
    v2f h2p[8];
#pragma unroll
    for (int j = 0; j < 8; ++j) {
        float r0 = eluf(dot16p(dl2w + (2*j+0)*16, yp, dl2b[2*j+0]));
        float r1 = eluf(dot16p(dl2w + (2*j+1)*16, yp, dl2b[2*j+1]));
        h2p[j] = {r0, r1};
    }
    float o16[16];
#pragma unroll
    for (int o = 0; o < 16; ++o) o16[o] = dot16p(dl3w + o*16, h2p, dl3b[o]);

    float4* op = reinterpret_cast<float4*>(out + (size_t)i * 16);
    op[0] = make_float4(o16[0],  o16[1],  o16[2],  o16[3]);
    op[1] = make_float4(o16[4],  o16[5],  o16[6],  o16[7]);
    op[2] = make_float4(o16[8],  o16[9],  o16[10], o16[11]);
    op[3] = make_float4(o16[12], o16[13], o16[14], o16[15]);
}

extern "C" void kernel_launch(void* const* d_in, const int* in_sizes, int n_in,
                              void* d_out, int out_size, void* d_ws, size_t ws_size,
                              hipStream_t stream)
{
    const float* x      = (const float*)d_in[0];
    const float* noise  = (const float*)d_in[1];
    const float* fading = (const float*)d_in[2];
    const float* ew1  = (const float*)d_in[3];
    const float* eb1  = (const float*)d_in[4];
    const float* ew2  = (const float*)d_in[5];
    const float* eb2  = (const float*)d_in[6];
    const float* bng  = (const float*)d_in[7];
    const float* bnb  = (const float*)d_in[8];
    const float* pc1w = (const float*)d_in[9];
    const float* pc1b = (const float*)d_in[10];
    const float* pc2w = (const float*)d_in[11];
    const float* pc2b = (const float*)d_in[12];
    const float* pc3w = (const float*)d_in[13];
    const float* pc3b = (const float*)d_in[14];
    const float* pc4w = (const float*)d_in[15];
    const float* pc4b = (const float*)d_in[16];
    const float* pc5w = (const float*)d_in[17];
    const float* pc5b = (const float*)d_in[18];
    const float* plw  = (const float*)d_in[19];
    const float* plb  = (const float*)d_in[20];
    const float* dc1w = (const float*)d_in[21];
    const float* dc1b = (const float*)d_in[22];
    const float* dc2w = (const float*)d_in[23];
    const float* dc2b = (const float*)d_in[24];
    const float* dc3w = (const float*)d_in[25];
    const float* dc3b = (const float*)d_in[26];
    const float* dc4w = (const float*)d_in[27];
    const float* dc4b = (const float*)d_in[28];
    const float* dl1w = (const float*)d_in[29];
    const float* dl1b = (const float*)d_in[30];
    const float* dl2w = (const float*)d_in[31];
    const float* dl2b = (const float*)d_in[32];
    const float* dl3w = (const float*)d_in[33];
    const float* dl3b = (const float*)d_in[34];

    int B = in_sizes[0] / 16;
    int nblk = (B + 255) / 256;

    float* partials = (float*)d_ws;                    // nblk*32
    float* bnp  = partials + (size_t)nblk * 32;        // 32
    float* pc2s = bnp + 32;                            // 512
    float* pc5s = pc2s + 512;                          // 768
    float* dl1s = pc5s + 768;                          // 1024
    float* pc1i = dl1s + 1024;                         // 128
    float* crt  = pc1i + 128;                          // B*16 (z -> cr in-place)

    kAW<<<nblk + 1, 256, 0, stream>>>(x, ew1, eb1, ew2, eb2, partials, crt, B,
                                      pc1w, pc2w, pc5w, dl1w,
                                      pc1i, pc2s, pc5s, dl1s);
    kB<<<1, 256, 0, stream>>>(partials, nblk, B, bng, bnb, bnp);
    kF<<<nblk, 256, 0, stream>>>(crt, fading, noise, bnp,
                                 pc1i, pc1b, pc2s, pc2b, pc3w, pc3b, pc4w, pc4b, pc5s, pc5b,
                                 plw, plb,
                                 dc1w, dc1b, dc2w, dc2b, dc3w, dc3b, dc4w, dc4b,
                                 dl1s, dl1b, dl2w, dl2b, dl3w, dl3b,
                                 (float*)d_out, B);
}